// Round 18
// baseline (400.825 us; speedup 1.0000x reference)
//
#include <hip/hip_runtime.h>

#define NBATCH 4
#define NS 2048
#define ND 1024
#define NH 8
#define HD 128
#define NFF 512
#define NE 8
#define NT 65536       /* B*S*H tokens */
#define NBS 8192       /* B*S rows */
#define MU_F 0.7f
#define LN_EPS_F 1e-5f
#define EPS_GATE 2e-3f

typedef __attribute__((ext_vector_type(4))) float f32x4;
typedef __attribute__((ext_vector_type(2))) double f64x2;
typedef __attribute__((ext_vector_type(8))) _Float16 f16x8;
typedef __attribute__((ext_vector_type(4))) _Float16 f16x4;
typedef __attribute__((ext_vector_type(2))) _Float16 f16x2;

__device__ __forceinline__ void gload_lds16(const void* g, void* l) {
  __builtin_amdgcn_global_load_lds(
      (const __attribute__((address_space(1))) unsigned int*)g,
      (__attribute__((address_space(3))) unsigned int*)l, 16, 0, 0);
}

// ONE kernel for all 4 weight transposes.
__global__ void tr_cvt_all_kernel(const float* __restrict__ split_W, const float* __restrict__ merge_W,
                                  const float* __restrict__ W1, const float* __restrict__ W2,
                                  _Float16* __restrict__ sWt, _Float16* __restrict__ mWt,
                                  _Float16* __restrict__ W1t, _Float16* __restrict__ W2t) {
  __shared__ float tile[32][33];
  int id = blockIdx.x;
  const float* in; _Float16* out; int R, C, bx, by, b;
  if (id < 1024)      { in = split_W; out = sWt; R = ND;  C = ND;  bx = id & 31; by = id >> 5; b = 0; }
  else if (id < 2048) { id -= 1024; in = merge_W; out = mWt; R = ND;  C = ND;  bx = id & 31; by = id >> 5; b = 0; }
  else if (id < 2560) { id -= 2048; in = W1; out = W1t; R = HD;  C = NFF; bx = id & 15; by = (id >> 4) & 3; b = id >> 6; }
  else                { id -= 2560; in = W2; out = W2t; R = NFF; C = HD;  bx = id & 3;  by = (id >> 2) & 15; b = id >> 6; }
  const float* inp = in + (size_t)b * R * C;
  _Float16* outp = out + (size_t)b * R * C;
  int c = bx * 32 + threadIdx.x;
  int r0 = by * 32;
  #pragma unroll
  for (int i = 0; i < 4; i++) {
    int r = r0 + threadIdx.y + i * 8;
    tile[threadIdx.y + i * 8][threadIdx.x] = inp[(size_t)r * C + c];
  }
  __syncthreads();
  int rr = r0 + threadIdx.x;
  #pragma unroll
  for (int i = 0; i < 4; i++) {
    int cc = bx * 32 + threadIdx.y + i * 8;
    outp[(size_t)cc * R + rr] = (_Float16)tile[threadIdx.x][threadIdx.y + i * 8];
  }
}

// one thread per G[d][o] scalar. Writes Gx2 (f64 pairs [kp][o], fallback path)
// AND Gf (f32 pairs [kp][o], fast path) + gbias. Zeroes cnt.
__global__ void build_G_kernel(const float* __restrict__ split_W, const float* __restrict__ split_b,
                               const float* __restrict__ gate_W, const float* __restrict__ gate_b,
                               double* __restrict__ G, float* __restrict__ Gf,
                               double* __restrict__ gbias, int* __restrict__ cnt) {
  int idx = blockIdx.x * 256 + threadIdx.x;   // = d*64 + o
  if (blockIdx.x == 0 && threadIdx.x < 256) { cnt[threadIdx.x] = 0; cnt[threadIdx.x + 256] = 0; }
  int d = idx >> 6, o = idx & 63, h = o >> 3, e = o & 7;
  double acc = 0.0;
  const float* r0 = split_W + (size_t)d * ND + h * 128;
  #pragma unroll 4
  for (int j = 0; j < 128; j++)
    acc += (double)r0[j] * (double)gate_W[j * 8 + e];
  size_t pk = ((size_t)(d >> 1) * 64 + o) * 2 + (d & 1);
  G[pk] = acc;
  Gf[pk] = (float)acc;
  if (idx < 64) {
    double bacc = 0.0;
    for (int j = 0; j < 128; j++)
      bacc += (double)split_b[h * 128 + j] * (double)gate_W[j * 8 + e];
    gbias[idx] = bacc + (double)gate_b[e];
  }
}

// gate v10: v6's PROVEN structure (LDS-staged chunks, broadcast-FMA loop) with
// fp32 data (float2 G b64 reads + float x broadcasts: ~2x less LDS-pipe time
// than v6's fp64 b128s) + fp64 guarded fallback (tokens with top1/2 or top2/3
// gap < EPS_GATE recompute 8 logits from Gx2 -> routing identical to fp64 gate;
// logic proven in r17). v9's scalar-load experiment REVERTED (s_load latency
// trap: 196us). Fused x->fp16 + hierarchical atomics kept.
__global__ __launch_bounds__(256) void gate_kernel(const float* __restrict__ x,
    const float* __restrict__ Gf, const f64x2* __restrict__ Gx2, const double* __restrict__ gbias,
    _Float16* __restrict__ x_h,
    float* __restrict__ tkw, int* __restrict__ lists, int* __restrict__ cnt) {
  __shared__ float Gsf[32 * 128];    // 16 KB: chunk of Gf, [kp][col-pair]
  __shared__ float xsf[16 * 68];     // 4.25 KB x chunk (fp32, stride 68)
  __shared__ float lg[16 * 64];      // 4 KB logits
  __shared__ int lcnt[8];
  __shared__ int lbase[8];
  int tid = threadIdx.x, lane = tid & 63, w = tid >> 6;
  int bs0 = blockIdx.x * 16;
  float accA[4], accB[4];
  #pragma unroll
  for (int r = 0; r < 4; r++) { accA[r] = 0.f; accB[r] = 0.f; }
  int xrow = tid >> 4, xc4 = tid & 15;
  const float* xr = xsf + (w * 4) * 68;
  if (tid < 8) lcnt[tid] = 0;

  for (int ch = 0; ch < 16; ch++) {
    __syncthreads();           // previous chunk's reads complete before overwrite
    // stage x chunk (16 rows x 64 k) + fused fp16 convert
    float4 xv4 = *(const float4*)(x + (size_t)(bs0 + xrow) * ND + ch * 64 + xc4 * 4);
    *(float4*)&xsf[xrow * 68 + xc4 * 4] = xv4;
    f16x4 xh = { (_Float16)xv4.x, (_Float16)xv4.y, (_Float16)xv4.z, (_Float16)xv4.w };
    *(f16x4*)(x_h + (size_t)(bs0 + xrow) * ND + ch * 64 + xc4 * 4) = xh;
    // async-stage Gf chunk (16 KB linear)
    #pragma unroll
    for (int j = 0; j < 4; j++) {
      int n = j * 256 + tid;           // 0..1023 16B granules
      gload_lds16(Gf + (size_t)ch * 4096 + n * 4, Gsf + n * 4);
    }
    __syncthreads();           // compiler drains vmcnt: G + x ready
    #pragma unroll 8
    for (int kp = 0; kp < 32; kp++) {
      float2 g = *(const float2*)&Gsf[kp * 128 + lane * 2];   // b64, conflict-free
      #pragma unroll
      for (int r = 0; r < 4; r++) {
        float2 xv = *(const float2*)(xr + r * 68 + kp * 2);   // LDS broadcast
        accA[r] = fmaf(xv.x, g.x, accA[r]);
        accB[r] = fmaf(xv.y, g.y, accB[r]);
      }
    }
  }
  float gbf = (float)gbias[lane];
  #pragma unroll
  for (int r = 0; r < 4; r++)
    lg[(w * 4 + r) * 64 + lane] = accA[r] + accB[r] + gbf;
  __syncthreads();

  int i1 = 0, i2 = 0, token = 0, p1 = 0, p2 = 0;
  if (tid < 128) {
    int row = tid >> 3, h = tid & 7;
    const float* L = lg + row * 64 + h * 8;
    float v1 = L[0];
    #pragma unroll
    for (int e2 = 1; e2 < 8; e2++) if (L[e2] > v1) { v1 = L[e2]; i1 = e2; }
    i2 = -1; float v2 = -1e30f;
    #pragma unroll
    for (int e2 = 0; e2 < 8; e2++) if (e2 != i1 && L[e2] > v2) { v2 = L[e2]; i2 = e2; }
    float v3 = -1e30f;
    #pragma unroll
    for (int e2 = 0; e2 < 8; e2++) if (e2 != i1 && e2 != i2 && L[e2] > v3) v3 = L[e2];
    float g1, g2;
    if ((v1 - v2 >= EPS_GATE) && (v2 - v3 >= EPS_GATE)) {
      float ex = expf(v2 - v1);
      float den = 1.f + ex;
      g1 = 1.f / den; g2 = ex / den;
    } else {
      // fp64 exact recompute of this token's 8 logits (rare)
      double L64[8];
      #pragma unroll
      for (int e2 = 0; e2 < 8; e2++) L64[e2] = gbias[h * 8 + e2];
      const float* xrg = x + (size_t)(bs0 + row) * ND;
      for (int kp = 0; kp < 512; kp++) {
        double x0 = (double)xrg[kp * 2], x1 = (double)xrg[kp * 2 + 1];
        const f64x2* gp = Gx2 + (size_t)kp * 64 + h * 8;
        #pragma unroll
        for (int e2 = 0; e2 < 8; e2++) {
          f64x2 g = gp[e2];
          L64[e2] += x0 * g.x + x1 * g.y;
        }
      }
      i1 = 0; double d1 = L64[0];
      #pragma unroll
      for (int e2 = 1; e2 < 8; e2++) if (L64[e2] > d1) { d1 = L64[e2]; i1 = e2; }
      i2 = -1; double d2 = -1e300;
      #pragma unroll
      for (int e2 = 0; e2 < 8; e2++) if (e2 != i1 && L64[e2] > d2) { d2 = L64[e2]; i2 = e2; }
      float ex = expf((float)(d2 - d1));
      float den = 1.f + ex;
      g1 = 1.f / den; g2 = ex / den;
    }
    token = (bs0 + row) * 8 + h;
    tkw[token * 2]     = g1;
    tkw[token * 2 + 1] = g2;
    p1 = atomicAdd(&lcnt[i1], 1);             // LDS atomics: cheap
    p2 = atomicAdd(&lcnt[i2], 1);
  }
  __syncthreads();
  if (tid < 8) lbase[tid] = atomicAdd(cnt + tid * 64, lcnt[tid]);   // 8 global atomics/block
  __syncthreads();
  if (tid < 128) {
    lists[(size_t)i1 * NT + lbase[i1] + p1] = token * 2;
    lists[(size_t)i2 * NT + lbase[i2] + p2] = token * 2 + 1;
  }
}

// C[M][N] = A[M][K] @ Bt[N][K]^T + bias; fp16 inputs, fp32 acc.
// 128x128 tile, BK=32, 4 waves, global_load_lds w16, XCD-chunked swizzle (T1).
__global__ __launch_bounds__(256) void gemm_f16_kernel(
    const _Float16* __restrict__ A, const _Float16* __restrict__ Bt,
    const float* __restrict__ bias, float* __restrict__ Cf, _Float16* __restrict__ Ch,
    int M, int N, int Kd) {
  __shared__ _Float16 As[128 * 32];
  __shared__ _Float16 Bs[128 * 32];
  int tid = threadIdx.x, lane = tid & 63, w = tid >> 6;
  int wr = w >> 1, wc = w & 1;
  int lid = blockIdx.y * 8 + blockIdx.x;        // dispatch order (x fastest)
  int xcd = lid & 7, sub = (lid >> 3) & 7, grp = lid >> 6;
  int m0 = (xcd * 8 + sub) * 128;               // contiguous A-panels per XCD
  int n0 = grp * 128;
  f32x4 acc[4][4];
  #pragma unroll
  for (int i = 0; i < 4; i++)
    #pragma unroll
    for (int j = 0; j < 4; j++) acc[i][j] = (f32x4){0.f, 0.f, 0.f, 0.f};
  int srow = lane >> 2, scol = (lane & 3) * 8;
  int fr = lane & 15, ko = (lane >> 4) * 8;
  const _Float16* Ag = A + (size_t)(m0 + srow) * Kd + scol;
  const _Float16* Bg = Bt + (size_t)(n0 + srow) * Kd + scol;

  for (int k0 = 0; k0 < Kd; k0 += 32) {
    #pragma unroll
    for (int j = 0; j < 2; j++) {
      int rb = (w * 2 + j) * 16;
      gload_lds16(Ag + (size_t)rb * Kd + k0, As + rb * 32);
      gload_lds16(Bg + (size_t)rb * Kd + k0, Bs + rb * 32);
    }
    __syncthreads();
    f16x8 af[4], bq[4];
    #pragma unroll
    for (int mi = 0; mi < 4; mi++) af[mi] = *(const f16x8*)(As + (wr * 64 + mi * 16 + fr) * 32 + ko);
    #pragma unroll
    for (int ni = 0; ni < 4; ni++) bq[ni] = *(const f16x8*)(Bs + (wc * 64 + ni * 16 + fr) * 32 + ko);
    __syncthreads();
    #pragma unroll
    for (int mi = 0; mi < 4; mi++)
      #pragma unroll
      for (int ni = 0; ni < 4; ni++)
        acc[mi][ni] = __builtin_amdgcn_mfma_f32_16x16x32_f16(af[mi], bq[ni], acc[mi][ni], 0, 0, 0);
  }
  int rbase = m0 + wr * 64 + ((lane >> 4) << 2);
  int cbase = n0 + wc * 64 + (lane & 15);
  #pragma unroll
  for (int mi = 0; mi < 4; mi++)
    #pragma unroll
    for (int ni = 0; ni < 4; ni++) {
      int cc = cbase + ni * 16;
      float bv = bias ? bias[cc] : 0.f;
      #pragma unroll
      for (int r = 0; r < 4; r++) {
        int rr = rbase + mi * 16 + r;
        float v = acc[mi][ni][r] + bv;
        if (Cf) Cf[(size_t)rr * N + cc] = v;
        if (Ch) Ch[(size_t)rr * N + cc] = (_Float16)v;
      }
    }
}

// Grouped expert kernel v9 = v7 + swapped-operand phase A (acc1 = mfma(bq, af)
// computes h^T: reg-quad = 4 consecutive ff for one token -> single b64 h-write).
// 3-ring counted-vmcnt staging; phase B/epilogue as v7.
__global__ __launch_bounds__(512, 2) void expert_kernel(
    const _Float16* __restrict__ t_h, const _Float16* __restrict__ W1t, const _Float16* __restrict__ W2t,
    const float* __restrict__ b1, const float* __restrict__ b2,
    const int* __restrict__ cnt, const int* __restrict__ lists, const float* __restrict__ tkw,
    _Float16* __restrict__ slots) {
  int e = blockIdx.x & 7;              // consecutive blocks -> different XCDs
  int m0 = (blockIdx.x >> 3) * 128;
  int count = cnt[e * 64];
  if (m0 >= count) return;
  __shared__ _Float16 ring[3][64 * 128];  // 3 x 16 KB staging ring
  __shared__ _Float16 h_s[128 * 64];      // 16 KB [tok128][ff64] 128B rows
  __shared__ float b1s[NFF];              // 2 KB
  __shared__ float b2s[HD];               // 512 B
  __shared__ int alist[128];
  __shared__ float aw[128];
  int tid = threadIdx.x, lane = tid & 63, w = tid >> 6;
  int wr = w >> 1, wc = w & 1;         // 4 row-quarters (32) x 2 col-halves (64)
  int fr = lane & 15, g = lane >> 4;

  if (tid < 128) {
    int idx = m0 + tid;
    int a = (idx < count) ? lists[(size_t)e * NT + idx] : -1;
    alist[tid] = a;
    aw[tid] = (a >= 0) ? tkw[a] : 0.f;
  }
  b1s[tid] = b1[e * NFF + tid];
  if (tid < 128) b2s[tid] = b2[e * HD + tid];
  __syncthreads();

  auto stage = [&](int p) {
    if (p >= 16) return;
    int ch = p >> 1;
    _Float16* dst = &ring[p % 3][0];
    if ((p & 1) == 0) {
      #pragma unroll
      for (int j = 0; j < 2; j++) {
        int n = j * 512 + tid;           // 16 granules per 256B row
        int r = n >> 4, gg = n & 15;
        int sg = gg ^ ((r >> 1) & 7);
        gload_lds16(W1t + (size_t)e * (NFF * HD) + (size_t)(ch * 64 + r) * HD + sg * 8, dst + n * 8);
      }
    } else {
      #pragma unroll
      for (int j = 0; j < 2; j++) {
        int n = j * 512 + tid;           // 8 granules per 128B row
        int r = n >> 3, gg = n & 7;
        int sg = gg ^ ((r >> 1) & 7);
        gload_lds16(W2t + (size_t)e * (HD * NFF) + (size_t)r * NFF + ch * 64 + sg * 8, dst + n * 8);
      }
    }
  };

  // gather this wave's 32 token rows into registers (held across all phases)
  f16x8 af[2][4];
  #pragma unroll
  for (int mi = 0; mi < 2; mi++) {
    int rloc = wr * 32 + mi * 16 + fr;
    int a = alist[rloc];
    const _Float16* tb = t_h + (size_t)(a >> 1) * HD;
    #pragma unroll
    for (int ks = 0; ks < 4; ks++) {
      f16x8 v = {0, 0, 0, 0, 0, 0, 0, 0};
      if (a >= 0) v = *(const f16x8*)(tb + ks * 32 + g * 8);
      af[mi][ks] = v;
    }
  }
  asm volatile("s_waitcnt vmcnt(0)" ::: "memory");   // drain gather: loop vmcnt is stage-only
  stage(0); stage(1);
  asm volatile("s_waitcnt vmcnt(2) lgkmcnt(0)\n\ts_barrier" ::: "memory");  // stage(0) landed

  f32x4 acc2[2][4];
  #pragma unroll
  for (int i = 0; i < 2; i++)
    #pragma unroll
    for (int j = 0; j < 4; j++) acc2[i][j] = (f32x4){0.f, 0.f, 0.f, 0.f};

  #pragma unroll
  for (int p = 0; p < 16; p++) {
    stage(p + 2);
    int ch = p >> 1;
    const char* WB = (const char*)&ring[p % 3][0];
    if ((p & 1) == 0) {
      // ---- A (swapped): acc1 = W1^T . t^T = h^T; reg-quad = 4 consecutive ff ----
      float b1r[2][4];
      #pragma unroll
      for (int ni = 0; ni < 2; ni++)
        #pragma unroll
        for (int r = 0; r < 4; r++)
          b1r[ni][r] = b1s[ch * 64 + wc * 32 + ni * 16 + g * 4 + r];
      f32x4 acc1[2][2];    // [mi tok-block][ni ff-block]
      #pragma unroll
      for (int i = 0; i < 2; i++)
        #pragma unroll
        for (int j = 0; j < 2; j++) acc1[i][j] = (f32x4){0.f, 0.f, 0.f, 0.f};
      #pragma unroll
      for (int ks = 0; ks < 4; ks++) {
        f16x8 bq[2];
        #pragma unroll
        for (int ni = 0; ni < 2; ni++) {
          int rw = wc * 32 + ni * 16 + fr;       // ff row of chunk (0..63)
          int byte = rw * 256 + ((ks * 64 + g * 16) ^ (((rw >> 1) & 7) << 4));
          bq[ni] = *(const f16x8*)(WB + byte);
        }
        #pragma unroll
        for (int mi = 0; mi < 2; mi++)
          #pragma unroll
          for (int ni = 0; ni < 2; ni++)
            acc1[mi][ni] = __builtin_amdgcn_mfma_f32_16x16x32_f16(bq[ni], af[mi][ks], acc1[mi][ni], 0, 0, 0);
      }
      // relu + bias -> pack 4 consecutive ff -> single b64 write per (mi,ni)
      #pragma unroll
      for (int mi = 0; mi < 2; mi++)
        #pragma unroll
        for (int ni = 0; ni < 2; ni++) {
          f16x4 hv;
          #pragma unroll
          for (int r = 0; r < 4; r++)
            hv[r] = (_Float16)fmaxf(acc1[mi][ni][r] + b1r[ni][r], 0.f);
          int tok = wr * 32 + mi * 16 + fr;
          int foff = wc * 64 + ni * 32 + g * 8;       // ff*2 bytes
          int byte = tok * 128 + (foff ^ (((tok >> 1) & 7) << 4));
          *(f16x4*)((char*)h_s + byte) = hv;
        }
    } else {
      // ---- B: acc2 += h(:, ch) @ W2chunk ----
      #pragma unroll
      for (int ks = 0; ks < 2; ks++) {
        f16x8 ah[2], bq[4];
        #pragma unroll
        for (int mi = 0; mi < 2; mi++) {
          int row = wr * 32 + mi * 16 + fr;
          int byte = row * 128 + ((ks * 64 + g * 16) ^ (((row >> 1) & 7) << 4));
          ah[mi] = *(const f16x8*)((const char*)h_s + byte);
        }
        #pragma unroll
        for (int ni = 0; ni < 4; ni++) {
          int rw = wc * 64 + ni * 16 + fr;       // d row (0..127)
          int byte = rw * 128 + ((ks * 64 + g * 16) ^ (((rw >> 1) & 7) << 4));
          bq[ni] = *(const f16x8*)((const char*)&ring[p % 3][0] + byte);
        }
        #pragma unroll
        for (int mi = 0; mi < 2; mi++)
          #pragma unroll
          for (int ni = 0; ni < 4; ni++)
            acc2[mi][ni] = __builtin_amdgcn_mfma_f32_16x16x32_f16(ah[mi], bq[ni], acc2[mi][ni], 0, 0, 0);
      }
    }
    if (p == 14) {
      asm volatile("s_waitcnt vmcnt(0) lgkmcnt(0)\n\ts_barrier" ::: "memory");
    } else if (p < 14) {
      asm volatile("s_waitcnt vmcnt(2) lgkmcnt(0)\n\ts_barrier" ::: "memory");
    }
  }
  // epilogue: gate-scale + fp16 scatter to slots
  #pragma unroll
  for (int mi = 0; mi < 2; mi++)
    #pragma unroll
    for (int ni = 0; ni < 4; ni++) {
      int ncol = wc * 64 + ni * 16 + fr;
      float bv = b2s[ncol];
      #pragma unroll
      for (int r = 0; r < 4; r++) {
        int m = wr * 32 + mi * 16 + g * 4 + r;
        int a = alist[m];
        if (a >= 0)
          slots[(size_t)a * HD + ncol] = (_Float16)(aw[m] * (acc2[mi][ni][r] + bv));
      }
    }
}

// combine slots -> momentum update -> residual -> LayerNorm
__global__ __launch_bounds__(256) void combine_ln_kernel(
    const _Float16* __restrict__ slots, const float* __restrict__ momentum,
    const _Float16* __restrict__ t_h, const float* __restrict__ ln_g, const float* __restrict__ ln_b,
    float* __restrict__ nm_out, _Float16* __restrict__ out_h) {
  int w = threadIdx.x >> 6, lane = threadIdx.x & 63;
  int tok = blockIdx.x * 4 + w;
  int d0 = lane * 2;
  f16x2 s0 = *(const f16x2*)(slots + (size_t)tok * 256 + d0);
  f16x2 s1 = *(const f16x2*)(slots + (size_t)tok * 256 + 128 + d0);
  float2 mo = *(const float2*)(momentum + (size_t)tok * HD + d0);
  f16x2 tv = *(const f16x2*)(t_h + (size_t)tok * HD + d0);
  float nm0 = -((float)s0.x + (float)s1.x) + MU_F * mo.x;
  float nm1 = -((float)s0.y + (float)s1.y) + MU_F * mo.y;
  float2 nm2; nm2.x = nm0; nm2.y = nm1;
  *(float2*)(nm_out + (size_t)tok * HD + d0) = nm2;
  float r0 = (float)tv.x + nm0;
  float r1 = (float)tv.y + nm1;
  float s = r0 + r1, sq = r0 * r0 + r1 * r1;
  #pragma unroll
  for (int m = 1; m < 64; m <<= 1) { s += __shfl_xor(s, m, 64); sq += __shfl_xor(sq, m, 64); }
  float mean = s * (1.f / 128.f);
  float var = sq * (1.f / 128.f) - mean * mean;
  float is = rsqrtf(var + LN_EPS_F);
  float y0 = (r0 - mean) * is * ln_g[d0] + ln_b[d0];
  float y1 = (r1 - mean) * is * ln_g[d0 + 1] + ln_b[d0 + 1];
  f16x2 yo = { (_Float16)y0, (_Float16)y1 };
  *(f16x2*)(out_h + (size_t)tok * HD + d0) = yo;
}

extern "C" void kernel_launch(void* const* d_in, const int* in_sizes, int n_in,
                              void* d_out, int out_size, void* d_ws, size_t ws_size,
                              hipStream_t stream) {
  const float* x        = (const float*)d_in[0];
  const float* momentum = (const float*)d_in[1];
  const float* split_W  = (const float*)d_in[2];
  const float* split_b  = (const float*)d_in[3];
  const float* gate_W   = (const float*)d_in[4];
  const float* gate_b   = (const float*)d_in[5];
  const float* W1       = (const float*)d_in[6];
  const float* b1       = (const float*)d_in[7];
  const float* W2       = (const float*)d_in[8];
  const float* b2       = (const float*)d_in[9];
  const float* ln_g     = (const float*)d_in[10];
  const float* ln_b     = (const float*)d_in[11];
  const float* merge_W  = (const float*)d_in[12];
  const float* merge_b  = (const float*)d_in[13];
  float* final_out = (float*)d_out;
  float* nm_out    = final_out + (size_t)NBS * ND;

  char* ws = (char*)d_ws;
  size_t off = 0;
  auto alloc = [&](size_t bytes) { void* p = ws + off; off = (off + bytes + 255) & ~(size_t)255; return p; };
  _Float16* x_h   = (_Float16*)alloc((size_t)NBS * ND * 2);
  _Float16* t_h   = (_Float16*)alloc((size_t)NT * HD * 2);
  _Float16* out_h = (_Float16*)alloc((size_t)NT * HD * 2);
  _Float16* sWt   = (_Float16*)alloc((size_t)ND * ND * 2);
  _Float16* mWt   = (_Float16*)alloc((size_t)ND * ND * 2);
  _Float16* W1t   = (_Float16*)alloc((size_t)NE * HD * NFF * 2);
  _Float16* W2t   = (_Float16*)alloc((size_t)NE * HD * NFF * 2);
  f64x2*    Gx2   = (f64x2*)alloc((size_t)512 * 64 * 16);
  float*    Gf    = (float*)alloc((size_t)512 * 64 * 8);
  double*   gbias = (double*)alloc(64 * 8);
  float*    tkw   = (float*)alloc((size_t)NT * 2 * 4);
  int*      lists = (int*)alloc((size_t)NE * NT * 4);
  int*      cnt   = (int*)alloc(512 * 4);
  _Float16* slots = (_Float16*)alloc((size_t)NT * 2 * HD * 2);
  (void)in_sizes; (void)n_in; (void)out_size; (void)ws_size;

  tr_cvt_all_kernel<<<3072, dim3(32, 8), 0, stream>>>(split_W, merge_W, W1, W2, sWt, mWt, W1t, W2t);
  build_G_kernel<<<256, 256, 0, stream>>>(split_W, split_b, gate_W, gate_b, (double*)Gx2, Gf, gbias, cnt);
  // gate also produces x_h (fused convert), so it runs before the split GEMM
  gate_kernel<<<512, 256, 0, stream>>>(x, Gf, Gx2, gbias, x_h, tkw, lists, cnt);
  // t = x @ split_W + split_b   (fp16 out for downstream MFMA)
  gemm_f16_kernel<<<dim3(8, 64), 256, 0, stream>>>(x_h, sWt, split_b, nullptr, t_h, NBS, ND, ND);
  expert_kernel<<<NE * 512, 512, 0, stream>>>(t_h, W1t, W2t, b1, b2, cnt, lists, tkw, slots);
  combine_ln_kernel<<<NT / 4, 256, 0, stream>>>(slots, momentum, t_h, ln_g, ln_b, nm_out, out_h);
  // final = out @ merge_W + merge_b
  gemm_f16_kernel<<<dim3(8, 64), 256, 0, stream>>>(out_h, mWt, merge_b, final_out, nullptr, NBS, ND, ND);
}

// Round 19
// 400.688 us; speedup vs baseline: 1.0003x; 1.0003x over previous
//
#include <hip/hip_runtime.h>

#define NBATCH 4
#define NS 2048
#define ND 1024
#define NH 8
#define HD 128
#define NFF 512
#define NE 8
#define NT 65536       /* B*S*H tokens */
#define NBS 8192       /* B*S rows */
#define MU_F 0.7f
#define LN_EPS_F 1e-5f
#define EPS_GATE 1e-4f

typedef __attribute__((ext_vector_type(4))) float f32x4;
typedef __attribute__((ext_vector_type(2))) double f64x2;
typedef __attribute__((ext_vector_type(8))) _Float16 f16x8;
typedef __attribute__((ext_vector_type(4))) _Float16 f16x4;
typedef __attribute__((ext_vector_type(2))) _Float16 f16x2;

__device__ __forceinline__ void gload_lds16(const void* g, void* l) {
  __builtin_amdgcn_global_load_lds(
      (const __attribute__((address_space(1))) unsigned int*)g,
      (__attribute__((address_space(3))) unsigned int*)l, 16, 0, 0);
}

// ONE kernel for all 4 weight transposes.
__global__ void tr_cvt_all_kernel(const float* __restrict__ split_W, const float* __restrict__ merge_W,
                                  const float* __restrict__ W1, const float* __restrict__ W2,
                                  _Float16* __restrict__ sWt, _Float16* __restrict__ mWt,
                                  _Float16* __restrict__ W1t, _Float16* __restrict__ W2t) {
  __shared__ float tile[32][33];
  int id = blockIdx.x;
  const float* in; _Float16* out; int R, C, bx, by, b;
  if (id < 1024)      { in = split_W; out = sWt; R = ND;  C = ND;  bx = id & 31; by = id >> 5; b = 0; }
  else if (id < 2048) { id -= 1024; in = merge_W; out = mWt; R = ND;  C = ND;  bx = id & 31; by = id >> 5; b = 0; }
  else if (id < 2560) { id -= 2048; in = W1; out = W1t; R = HD;  C = NFF; bx = id & 15; by = (id >> 4) & 3; b = id >> 6; }
  else                { id -= 2560; in = W2; out = W2t; R = NFF; C = HD;  bx = id & 3;  by = (id >> 2) & 15; b = id >> 6; }
  const float* inp = in + (size_t)b * R * C;
  _Float16* outp = out + (size_t)b * R * C;
  int c = bx * 32 + threadIdx.x;
  int r0 = by * 32;
  #pragma unroll
  for (int i = 0; i < 4; i++) {
    int r = r0 + threadIdx.y + i * 8;
    tile[threadIdx.y + i * 8][threadIdx.x] = inp[(size_t)r * C + c];
  }
  __syncthreads();
  int rr = r0 + threadIdx.x;
  #pragma unroll
  for (int i = 0; i < 4; i++) {
    int cc = bx * 32 + threadIdx.y + i * 8;
    outp[(size_t)cc * R + rr] = (_Float16)tile[threadIdx.x][threadIdx.y + i * 8];
  }
}

// one thread per G[d][o] scalar. Writes Gx2 (f64 pairs [kp][o], fallback path)
// AND Gq (f32 [kquad][o][4], fast path: one float4 = 4 consecutive k for col o)
// + gbias. Zeroes cnt.
__global__ void build_G_kernel(const float* __restrict__ split_W, const float* __restrict__ split_b,
                               const float* __restrict__ gate_W, const float* __restrict__ gate_b,
                               double* __restrict__ G, float* __restrict__ Gq,
                               double* __restrict__ gbias, int* __restrict__ cnt) {
  int idx = blockIdx.x * 256 + threadIdx.x;   // = d*64 + o
  if (blockIdx.x == 0 && threadIdx.x < 256) { cnt[threadIdx.x] = 0; cnt[threadIdx.x + 256] = 0; }
  int d = idx >> 6, o = idx & 63, h = o >> 3, e = o & 7;
  double acc = 0.0;
  const float* r0 = split_W + (size_t)d * ND + h * 128;
  #pragma unroll 4
  for (int j = 0; j < 128; j++)
    acc += (double)r0[j] * (double)gate_W[j * 8 + e];
  G[((size_t)(d >> 1) * 64 + o) * 2 + (d & 1)] = acc;
  Gq[((size_t)(d >> 2) * 64 + o) * 4 + (d & 3)] = (float)acc;
  if (idx < 64) {
    double bacc = 0.0;
    for (int j = 0; j < 128; j++)
      bacc += (double)split_b[h * 128 + j] * (double)gate_W[j * 8 + e];
    gbias[idx] = bacc + (double)gate_b[e];
  }
}

// gate v11: fp32 main loop, Gq float4 layout (1 G b128 + 4 x-float4 broadcasts
// per 4 k = 1.25 LDS ops/k, half of v6/v10's 2.5 -- LDS time scales with
// instruction COUNT not width, m134) + fp64 guarded fallback at EPS=1e-4.
// EPS rationale: deterministic fp32 logit error <= ~2e-5 (1024-term dot), so
// gap >= 1e-4 guarantees identical routing; trigger rate ~20x lower than the
// r17/r18 EPS=2e-3 disaster (wave-granularity amplification made ~57% of waves
// run the 512-iter fallback). Routing correctness of the guard proven r17/r18
// (absmax identical to fp64 gate). Fused x->fp16 + hierarchical atomics.
__global__ __launch_bounds__(256) void gate_kernel(const float* __restrict__ x,
    const float* __restrict__ Gq, const f64x2* __restrict__ Gx2, const double* __restrict__ gbias,
    _Float16* __restrict__ x_h,
    float* __restrict__ tkw, int* __restrict__ lists, int* __restrict__ cnt) {
  __shared__ float Gsq[16 * 256];    // 16 KB: chunk (16 kquads x 64 cols x 4)
  __shared__ float xsf[16 * 68];     // 4.25 KB x chunk (fp32, stride 68)
  __shared__ float lg[16 * 64];      // 4 KB logits
  __shared__ int lcnt[8];
  __shared__ int lbase[8];
  int tid = threadIdx.x, lane = tid & 63, w = tid >> 6;
  int bs0 = blockIdx.x * 16;
  float accA[4], accB[4];
  #pragma unroll
  for (int r = 0; r < 4; r++) { accA[r] = 0.f; accB[r] = 0.f; }
  int xrow = tid >> 4, xc4 = tid & 15;
  const float* xr = xsf + (w * 4) * 68;
  if (tid < 8) lcnt[tid] = 0;

  for (int ch = 0; ch < 16; ch++) {
    __syncthreads();           // previous chunk's reads complete before overwrite
    // stage x chunk (16 rows x 64 k) + fused fp16 convert
    float4 xv4 = *(const float4*)(x + (size_t)(bs0 + xrow) * ND + ch * 64 + xc4 * 4);
    *(float4*)&xsf[xrow * 68 + xc4 * 4] = xv4;
    f16x4 xh = { (_Float16)xv4.x, (_Float16)xv4.y, (_Float16)xv4.z, (_Float16)xv4.w };
    *(f16x4*)(x_h + (size_t)(bs0 + xrow) * ND + ch * 64 + xc4 * 4) = xh;
    // async-stage Gq chunk (16 KB linear)
    #pragma unroll
    for (int j = 0; j < 4; j++) {
      int n = j * 256 + tid;           // 0..1023 16B granules
      gload_lds16(Gq + (size_t)ch * 4096 + n * 4, Gsq + n * 4);
    }
    __syncthreads();           // compiler drains vmcnt: G + x ready
    #pragma unroll 4
    for (int kq = 0; kq < 16; kq++) {
      float4 g = *(const float4*)&Gsq[kq * 256 + lane * 4];   // b128, coalesced LDS
      #pragma unroll
      for (int r = 0; r < 4; r++) {
        float4 xv = *(const float4*)(xr + r * 68 + kq * 4);   // b128 broadcast
        accA[r] = fmaf(xv.x, g.x, accA[r]);
        accB[r] = fmaf(xv.y, g.y, accB[r]);
        accA[r] = fmaf(xv.z, g.z, accA[r]);
        accB[r] = fmaf(xv.w, g.w, accB[r]);
      }
    }
  }
  float gbf = (float)gbias[lane];
  #pragma unroll
  for (int r = 0; r < 4; r++)
    lg[(w * 4 + r) * 64 + lane] = accA[r] + accB[r] + gbf;
  __syncthreads();

  int i1 = 0, i2 = 0, token = 0, p1 = 0, p2 = 0;
  if (tid < 128) {
    int row = tid >> 3, h = tid & 7;
    const float* L = lg + row * 64 + h * 8;
    float v1 = L[0];
    #pragma unroll
    for (int e2 = 1; e2 < 8; e2++) if (L[e2] > v1) { v1 = L[e2]; i1 = e2; }
    i2 = -1; float v2 = -1e30f;
    #pragma unroll
    for (int e2 = 0; e2 < 8; e2++) if (e2 != i1 && L[e2] > v2) { v2 = L[e2]; i2 = e2; }
    float v3 = -1e30f;
    #pragma unroll
    for (int e2 = 0; e2 < 8; e2++) if (e2 != i1 && e2 != i2 && L[e2] > v3) v3 = L[e2];
    float g1, g2;
    if ((v1 - v2 >= EPS_GATE) && (v2 - v3 >= EPS_GATE)) {
      float ex = expf(v2 - v1);
      float den = 1.f + ex;
      g1 = 1.f / den; g2 = ex / den;
    } else {
      // fp64 exact recompute of this token's 8 logits (rare: ~0.1% of tokens)
      double L64[8];
      #pragma unroll
      for (int e2 = 0; e2 < 8; e2++) L64[e2] = gbias[h * 8 + e2];
      const float* xrg = x + (size_t)(bs0 + row) * ND;
      for (int kp = 0; kp < 512; kp++) {
        double x0 = (double)xrg[kp * 2], x1 = (double)xrg[kp * 2 + 1];
        const f64x2* gp = Gx2 + (size_t)kp * 64 + h * 8;
        #pragma unroll
        for (int e2 = 0; e2 < 8; e2++) {
          f64x2 g = gp[e2];
          L64[e2] += x0 * g.x + x1 * g.y;
        }
      }
      i1 = 0; double d1 = L64[0];
      #pragma unroll
      for (int e2 = 1; e2 < 8; e2++) if (L64[e2] > d1) { d1 = L64[e2]; i1 = e2; }
      i2 = -1; double d2 = -1e300;
      #pragma unroll
      for (int e2 = 0; e2 < 8; e2++) if (e2 != i1 && L64[e2] > d2) { d2 = L64[e2]; i2 = e2; }
      float ex = expf((float)(d2 - d1));
      float den = 1.f + ex;
      g1 = 1.f / den; g2 = ex / den;
    }
    token = (bs0 + row) * 8 + h;
    tkw[token * 2]     = g1;
    tkw[token * 2 + 1] = g2;
    p1 = atomicAdd(&lcnt[i1], 1);             // LDS atomics: cheap
    p2 = atomicAdd(&lcnt[i2], 1);
  }
  __syncthreads();
  if (tid < 8) lbase[tid] = atomicAdd(cnt + tid * 64, lcnt[tid]);   // 8 global atomics/block
  __syncthreads();
  if (tid < 128) {
    lists[(size_t)i1 * NT + lbase[i1] + p1] = token * 2;
    lists[(size_t)i2 * NT + lbase[i2] + p2] = token * 2 + 1;
  }
}

// C[M][N] = A[M][K] @ Bt[N][K]^T + bias; fp16 inputs, fp32 acc.
// 128x128 tile, BK=32, 4 waves, global_load_lds w16, XCD-chunked swizzle (T1).
__global__ __launch_bounds__(256) void gemm_f16_kernel(
    const _Float16* __restrict__ A, const _Float16* __restrict__ Bt,
    const float* __restrict__ bias, float* __restrict__ Cf, _Float16* __restrict__ Ch,
    int M, int N, int Kd) {
  __shared__ _Float16 As[128 * 32];
  __shared__ _Float16 Bs[128 * 32];
  int tid = threadIdx.x, lane = tid & 63, w = tid >> 6;
  int wr = w >> 1, wc = w & 1;
  int lid = blockIdx.y * 8 + blockIdx.x;        // dispatch order (x fastest)
  int xcd = lid & 7, sub = (lid >> 3) & 7, grp = lid >> 6;
  int m0 = (xcd * 8 + sub) * 128;               // contiguous A-panels per XCD
  int n0 = grp * 128;
  f32x4 acc[4][4];
  #pragma unroll
  for (int i = 0; i < 4; i++)
    #pragma unroll
    for (int j = 0; j < 4; j++) acc[i][j] = (f32x4){0.f, 0.f, 0.f, 0.f};
  int srow = lane >> 2, scol = (lane & 3) * 8;
  int fr = lane & 15, ko = (lane >> 4) * 8;
  const _Float16* Ag = A + (size_t)(m0 + srow) * Kd + scol;
  const _Float16* Bg = Bt + (size_t)(n0 + srow) * Kd + scol;

  for (int k0 = 0; k0 < Kd; k0 += 32) {
    #pragma unroll
    for (int j = 0; j < 2; j++) {
      int rb = (w * 2 + j) * 16;
      gload_lds16(Ag + (size_t)rb * Kd + k0, As + rb * 32);
      gload_lds16(Bg + (size_t)rb * Kd + k0, Bs + rb * 32);
    }
    __syncthreads();
    f16x8 af[4], bq[4];
    #pragma unroll
    for (int mi = 0; mi < 4; mi++) af[mi] = *(const f16x8*)(As + (wr * 64 + mi * 16 + fr) * 32 + ko);
    #pragma unroll
    for (int ni = 0; ni < 4; ni++) bq[ni] = *(const f16x8*)(Bs + (wc * 64 + ni * 16 + fr) * 32 + ko);
    __syncthreads();
    #pragma unroll
    for (int mi = 0; mi < 4; mi++)
      #pragma unroll
      for (int ni = 0; ni < 4; ni++)
        acc[mi][ni] = __builtin_amdgcn_mfma_f32_16x16x32_f16(af[mi], bq[ni], acc[mi][ni], 0, 0, 0);
  }
  int rbase = m0 + wr * 64 + ((lane >> 4) << 2);
  int cbase = n0 + wc * 64 + (lane & 15);
  #pragma unroll
  for (int mi = 0; mi < 4; mi++)
    #pragma unroll
    for (int ni = 0; ni < 4; ni++) {
      int cc = cbase + ni * 16;
      float bv = bias ? bias[cc] : 0.f;
      #pragma unroll
      for (int r = 0; r < 4; r++) {
        int rr = rbase + mi * 16 + r;
        float v = acc[mi][ni][r] + bv;
        if (Cf) Cf[(size_t)rr * N + cc] = v;
        if (Ch) Ch[(size_t)rr * N + cc] = (_Float16)v;
      }
    }
}

// Grouped expert kernel v9 = v7 + swapped-operand phase A (acc1 = mfma(bq, af)
// computes h^T: reg-quad = 4 consecutive ff for one token -> single b64 h-write).
// 3-ring counted-vmcnt staging; phase B/epilogue as v7.
__global__ __launch_bounds__(512, 2) void expert_kernel(
    const _Float16* __restrict__ t_h, const _Float16* __restrict__ W1t, const _Float16* __restrict__ W2t,
    const float* __restrict__ b1, const float* __restrict__ b2,
    const int* __restrict__ cnt, const int* __restrict__ lists, const float* __restrict__ tkw,
    _Float16* __restrict__ slots) {
  int e = blockIdx.x & 7;              // consecutive blocks -> different XCDs
  int m0 = (blockIdx.x >> 3) * 128;
  int count = cnt[e * 64];
  if (m0 >= count) return;
  __shared__ _Float16 ring[3][64 * 128];  // 3 x 16 KB staging ring
  __shared__ _Float16 h_s[128 * 64];      // 16 KB [tok128][ff64] 128B rows
  __shared__ float b1s[NFF];              // 2 KB
  __shared__ float b2s[HD];               // 512 B
  __shared__ int alist[128];
  __shared__ float aw[128];
  int tid = threadIdx.x, lane = tid & 63, w = tid >> 6;
  int wr = w >> 1, wc = w & 1;         // 4 row-quarters (32) x 2 col-halves (64)
  int fr = lane & 15, g = lane >> 4;

  if (tid < 128) {
    int idx = m0 + tid;
    int a = (idx < count) ? lists[(size_t)e * NT + idx] : -1;
    alist[tid] = a;
    aw[tid] = (a >= 0) ? tkw[a] : 0.f;
  }
  b1s[tid] = b1[e * NFF + tid];
  if (tid < 128) b2s[tid] = b2[e * HD + tid];
  __syncthreads();

  auto stage = [&](int p) {
    if (p >= 16) return;
    int ch = p >> 1;
    _Float16* dst = &ring[p % 3][0];
    if ((p & 1) == 0) {
      #pragma unroll
      for (int j = 0; j < 2; j++) {
        int n = j * 512 + tid;           // 16 granules per 256B row
        int r = n >> 4, gg = n & 15;
        int sg = gg ^ ((r >> 1) & 7);
        gload_lds16(W1t + (size_t)e * (NFF * HD) + (size_t)(ch * 64 + r) * HD + sg * 8, dst + n * 8);
      }
    } else {
      #pragma unroll
      for (int j = 0; j < 2; j++) {
        int n = j * 512 + tid;           // 8 granules per 128B row
        int r = n >> 3, gg = n & 7;
        int sg = gg ^ ((r >> 1) & 7);
        gload_lds16(W2t + (size_t)e * (HD * NFF) + (size_t)r * NFF + ch * 64 + sg * 8, dst + n * 8);
      }
    }
  };

  // gather this wave's 32 token rows into registers (held across all phases)
  f16x8 af[2][4];
  #pragma unroll
  for (int mi = 0; mi < 2; mi++) {
    int rloc = wr * 32 + mi * 16 + fr;
    int a = alist[rloc];
    const _Float16* tb = t_h + (size_t)(a >> 1) * HD;
    #pragma unroll
    for (int ks = 0; ks < 4; ks++) {
      f16x8 v = {0, 0, 0, 0, 0, 0, 0, 0};
      if (a >= 0) v = *(const f16x8*)(tb + ks * 32 + g * 8);
      af[mi][ks] = v;
    }
  }
  asm volatile("s_waitcnt vmcnt(0)" ::: "memory");   // drain gather: loop vmcnt is stage-only
  stage(0); stage(1);
  asm volatile("s_waitcnt vmcnt(2) lgkmcnt(0)\n\ts_barrier" ::: "memory");  // stage(0) landed

  f32x4 acc2[2][4];
  #pragma unroll
  for (int i = 0; i < 2; i++)
    #pragma unroll
    for (int j = 0; j < 4; j++) acc2[i][j] = (f32x4){0.f, 0.f, 0.f, 0.f};

  #pragma unroll
  for (int p = 0; p < 16; p++) {
    stage(p + 2);
    int ch = p >> 1;
    const char* WB = (const char*)&ring[p % 3][0];
    if ((p & 1) == 0) {
      // ---- A (swapped): acc1 = W1^T . t^T = h^T; reg-quad = 4 consecutive ff ----
      float b1r[2][4];
      #pragma unroll
      for (int ni = 0; ni < 2; ni++)
        #pragma unroll
        for (int r = 0; r < 4; r++)
          b1r[ni][r] = b1s[ch * 64 + wc * 32 + ni * 16 + g * 4 + r];
      f32x4 acc1[2][2];    // [mi tok-block][ni ff-block]
      #pragma unroll
      for (int i = 0; i < 2; i++)
        #pragma unroll
        for (int j = 0; j < 2; j++) acc1[i][j] = (f32x4){0.f, 0.f, 0.f, 0.f};
      #pragma unroll
      for (int ks = 0; ks < 4; ks++) {
        f16x8 bq[2];
        #pragma unroll
        for (int ni = 0; ni < 2; ni++) {
          int rw = wc * 32 + ni * 16 + fr;       // ff row of chunk (0..63)
          int byte = rw * 256 + ((ks * 64 + g * 16) ^ (((rw >> 1) & 7) << 4));
          bq[ni] = *(const f16x8*)(WB + byte);
        }
        #pragma unroll
        for (int mi = 0; mi < 2; mi++)
          #pragma unroll
          for (int ni = 0; ni < 2; ni++)
            acc1[mi][ni] = __builtin_amdgcn_mfma_f32_16x16x32_f16(bq[ni], af[mi][ks], acc1[mi][ni], 0, 0, 0);
      }
      // relu + bias -> pack 4 consecutive ff -> single b64 write per (mi,ni)
      #pragma unroll
      for (int mi = 0; mi < 2; mi++)
        #pragma unroll
        for (int ni = 0; ni < 2; ni++) {
          f16x4 hv;
          #pragma unroll
          for (int r = 0; r < 4; r++)
            hv[r] = (_Float16)fmaxf(acc1[mi][ni][r] + b1r[ni][r], 0.f);
          int tok = wr * 32 + mi * 16 + fr;
          int foff = wc * 64 + ni * 32 + g * 8;       // ff*2 bytes
          int byte = tok * 128 + (foff ^ (((tok >> 1) & 7) << 4));
          *(f16x4*)((char*)h_s + byte) = hv;
        }
    } else {
      // ---- B: acc2 += h(:, ch) @ W2chunk ----
      #pragma unroll
      for (int ks = 0; ks < 2; ks++) {
        f16x8 ah[2], bq[4];
        #pragma unroll
        for (int mi = 0; mi < 2; mi++) {
          int row = wr * 32 + mi * 16 + fr;
          int byte = row * 128 + ((ks * 64 + g * 16) ^ (((row >> 1) & 7) << 4));
          ah[mi] = *(const f16x8*)((const char*)h_s + byte);
        }
        #pragma unroll
        for (int ni = 0; ni < 4; ni++) {
          int rw = wc * 64 + ni * 16 + fr;       // d row (0..127)
          int byte = rw * 128 + ((ks * 64 + g * 16) ^ (((rw >> 1) & 7) << 4));
          bq[ni] = *(const f16x8*)((const char*)&ring[p % 3][0] + byte);
        }
        #pragma unroll
        for (int mi = 0; mi < 2; mi++)
          #pragma unroll
          for (int ni = 0; ni < 4; ni++)
            acc2[mi][ni] = __builtin_amdgcn_mfma_f32_16x16x32_f16(ah[mi], bq[ni], acc2[mi][ni], 0, 0, 0);
      }
    }
    if (p == 14) {
      asm volatile("s_waitcnt vmcnt(0) lgkmcnt(0)\n\ts_barrier" ::: "memory");
    } else if (p < 14) {
      asm volatile("s_waitcnt vmcnt(2) lgkmcnt(0)\n\ts_barrier" ::: "memory");
    }
  }
  // epilogue: gate-scale + fp16 scatter to slots
  #pragma unroll
  for (int mi = 0; mi < 2; mi++)
    #pragma unroll
    for (int ni = 0; ni < 4; ni++) {
      int ncol = wc * 64 + ni * 16 + fr;
      float bv = b2s[ncol];
      #pragma unroll
      for (int r = 0; r < 4; r++) {
        int m = wr * 32 + mi * 16 + g * 4 + r;
        int a = alist[m];
        if (a >= 0)
          slots[(size_t)a * HD + ncol] = (_Float16)(aw[m] * (acc2[mi][ni][r] + bv));
      }
    }
}

// combine slots -> momentum update -> residual -> LayerNorm
__global__ __launch_bounds__(256) void combine_ln_kernel(
    const _Float16* __restrict__ slots, const float* __restrict__ momentum,
    const _Float16* __restrict__ t_h, const float* __restrict__ ln_g, const float* __restrict__ ln_b,
    float* __restrict__ nm_out, _Float16* __restrict__ out_h) {
  int w = threadIdx.x >> 6, lane = threadIdx.x & 63;
  int tok = blockIdx.x * 4 + w;
  int d0 = lane * 2;
  f16x2 s0 = *(const f16x2*)(slots + (size_t)tok * 256 + d0);
  f16x2 s1 = *(const f16x2*)(slots + (size_t)tok * 256 + 128 + d0);
  float2 mo = *(const float2*)(momentum + (size_t)tok * HD + d0);
  f16x2 tv = *(const f16x2*)(t_h + (size_t)tok * HD + d0);
  float nm0 = -((float)s0.x + (float)s1.x) + MU_F * mo.x;
  float nm1 = -((float)s0.y + (float)s1.y) + MU_F * mo.y;
  float2 nm2; nm2.x = nm0; nm2.y = nm1;
  *(float2*)(nm_out + (size_t)tok * HD + d0) = nm2;
  float r0 = (float)tv.x + nm0;
  float r1 = (float)tv.y + nm1;
  float s = r0 + r1, sq = r0 * r0 + r1 * r1;
  #pragma unroll
  for (int m = 1; m < 64; m <<= 1) { s += __shfl_xor(s, m, 64); sq += __shfl_xor(sq, m, 64); }
  float mean = s * (1.f / 128.f);
  float var = sq * (1.f / 128.f) - mean * mean;
  float is = rsqrtf(var + LN_EPS_F);
  float y0 = (r0 - mean) * is * ln_g[d0] + ln_b[d0];
  float y1 = (r1 - mean) * is * ln_g[d0 + 1] + ln_b[d0 + 1];
  f16x2 yo = { (_Float16)y0, (_Float16)y1 };
  *(f16x2*)(out_h + (size_t)tok * HD + d0) = yo;
}

extern "C" void kernel_launch(void* const* d_in, const int* in_sizes, int n_in,
                              void* d_out, int out_size, void* d_ws, size_t ws_size,
                              hipStream_t stream) {
  const float* x        = (const float*)d_in[0];
  const float* momentum = (const float*)d_in[1];
  const float* split_W  = (const float*)d_in[2];
  const float* split_b  = (const float*)d_in[3];
  const float* gate_W   = (const float*)d_in[4];
  const float* gate_b   = (const float*)d_in[5];
  const float* W1       = (const float*)d_in[6];
  const float* b1       = (const float*)d_in[7];
  const float* W2       = (const float*)d_in[8];
  const float* b2       = (const float*)d_in[9];
  const float* ln_g     = (const float*)d_in[10];
  const float* ln_b     = (const float*)d_in[11];
  const float* merge_W  = (const float*)d_in[12];
  const float* merge_b  = (const float*)d_in[13];
  float* final_out = (float*)d_out;
  float* nm_out    = final_out + (size_t)NBS * ND;

  char* ws = (char*)d_ws;
  size_t off = 0;
  auto alloc = [&](size_t bytes) { void* p = ws + off; off = (off + bytes + 255) & ~(size_t)255; return p; };
  _Float16* x_h   = (_Float16*)alloc((size_t)NBS * ND * 2);
  _Float16* t_h   = (_Float16*)alloc((size_t)NT * HD * 2);
  _Float16* out_h = (_Float16*)alloc((size_t)NT * HD * 2);
  _Float16* sWt   = (_Float16*)alloc((size_t)ND * ND * 2);
  _Float16* mWt   = (_Float16*)alloc((size_t)ND * ND * 2);
  _Float16* W1t   = (_Float16*)alloc((size_t)NE * HD * NFF * 2);
  _Float16* W2t   = (_Float16*)alloc((size_t)NE * HD * NFF * 2);
  f64x2*    Gx2   = (f64x2*)alloc((size_t)512 * 64 * 16);
  float*    Gq    = (float*)alloc((size_t)512 * 64 * 8);
  double*   gbias = (double*)alloc(64 * 8);
  float*    tkw   = (float*)alloc((size_t)NT * 2 * 4);
  int*      lists = (int*)alloc((size_t)NE * NT * 4);
  int*      cnt   = (int*)alloc(512 * 4);
  _Float16* slots = (_Float16*)alloc((size_t)NT * 2 * HD * 2);
  (void)in_sizes; (void)n_in; (void)out_size; (void)ws_size;

  tr_cvt_all_kernel<<<3072, dim3(32, 8), 0, stream>>>(split_W, merge_W, W1, W2, sWt, mWt, W1t, W2t);
  build_G_kernel<<<256, 256, 0, stream>>>(split_W, split_b, gate_W, gate_b, (double*)Gx2, Gq, gbias, cnt);
  // gate also produces x_h (fused convert), so it runs before the split GEMM
  gate_kernel<<<512, 256, 0, stream>>>(x, Gq, Gx2, gbias, x_h, tkw, lists, cnt);
  // t = x @ split_W + split_b   (fp16 out for downstream MFMA)
  gemm_f16_kernel<<<dim3(8, 64), 256, 0, stream>>>(x_h, sWt, split_b, nullptr, t_h, NBS, ND, ND);
  expert_kernel<<<NE * 512, 512, 0, stream>>>(t_h, W1t, W2t, b1, b2, cnt, lists, tkw, slots);
  combine_ln_kernel<<<NT / 4, 256, 0, stream>>>(slots, momentum, t_h, ln_g, ln_b, nm_out, out_h);
  // final = out @ merge_W + merge_b
  gemm_f16_kernel<<<dim3(8, 64), 256, 0, stream>>>(out_h, mWt, merge_b, final_out, nullptr, NBS, ND, ND);
}

// Round 20
// 220.340 us; speedup vs baseline: 1.8191x; 1.8185x over previous
//
#include <hip/hip_runtime.h>

#define NBATCH 4
#define NS 2048
#define ND 1024
#define NH 8
#define HD 128
#define NFF 512
#define NE 8
#define NT 65536       /* B*S*H tokens */
#define NBS 8192       /* B*S rows */
#define MU_F 0.7f
#define LN_EPS_F 1e-5f
#define EPS_GATE 1e-4f

typedef __attribute__((ext_vector_type(4))) float f32x4;
typedef __attribute__((ext_vector_type(2))) double f64x2;
typedef __attribute__((ext_vector_type(8))) _Float16 f16x8;
typedef __attribute__((ext_vector_type(4))) _Float16 f16x4;
typedef __attribute__((ext_vector_type(2))) _Float16 f16x2;

__device__ __forceinline__ void gload_lds16(const void* g, void* l) {
  __builtin_amdgcn_global_load_lds(
      (const __attribute__((address_space(1))) unsigned int*)g,
      (__attribute__((address_space(3))) unsigned int*)l, 16, 0, 0);
}

// ONE kernel for all 4 weight transposes.
__global__ void tr_cvt_all_kernel(const float* __restrict__ split_W, const float* __restrict__ merge_W,
                                  const float* __restrict__ W1, const float* __restrict__ W2,
                                  _Float16* __restrict__ sWt, _Float16* __restrict__ mWt,
                                  _Float16* __restrict__ W1t, _Float16* __restrict__ W2t) {
  __shared__ float tile[32][33];
  int id = blockIdx.x;
  const float* in; _Float16* out; int R, C, bx, by, b;
  if (id < 1024)      { in = split_W; out = sWt; R = ND;  C = ND;  bx = id & 31; by = id >> 5; b = 0; }
  else if (id < 2048) { id -= 1024; in = merge_W; out = mWt; R = ND;  C = ND;  bx = id & 31; by = id >> 5; b = 0; }
  else if (id < 2560) { id -= 2048; in = W1; out = W1t; R = HD;  C = NFF; bx = id & 15; by = (id >> 4) & 3; b = id >> 6; }
  else                { id -= 2560; in = W2; out = W2t; R = NFF; C = HD;  bx = id & 3;  by = (id >> 2) & 15; b = id >> 6; }
  const float* inp = in + (size_t)b * R * C;
  _Float16* outp = out + (size_t)b * R * C;
  int c = bx * 32 + threadIdx.x;
  int r0 = by * 32;
  #pragma unroll
  for (int i = 0; i < 4; i++) {
    int r = r0 + threadIdx.y + i * 8;
    tile[threadIdx.y + i * 8][threadIdx.x] = inp[(size_t)r * C + c];
  }
  __syncthreads();
  int rr = r0 + threadIdx.x;
  #pragma unroll
  for (int i = 0; i < 4; i++) {
    int cc = bx * 32 + threadIdx.y + i * 8;
    outp[(size_t)cc * R + rr] = (_Float16)tile[threadIdx.x][threadIdx.y + i * 8];
  }
}

// one thread per G[d][o] scalar. Writes Gx2 (f64 pairs [kp][o], fallback path)
// AND Gq (f32 [kquad][o][4], fast path) + gbias. Zeroes cnt.
__global__ void build_G_kernel(const float* __restrict__ split_W, const float* __restrict__ split_b,
                               const float* __restrict__ gate_W, const float* __restrict__ gate_b,
                               double* __restrict__ G, float* __restrict__ Gq,
                               double* __restrict__ gbias, int* __restrict__ cnt) {
  int idx = blockIdx.x * 256 + threadIdx.x;   // = d*64 + o
  if (blockIdx.x == 0 && threadIdx.x < 256) { cnt[threadIdx.x] = 0; cnt[threadIdx.x + 256] = 0; }
  int d = idx >> 6, o = idx & 63, h = o >> 3, e = o & 7;
  double acc = 0.0;
  const float* r0 = split_W + (size_t)d * ND + h * 128;
  #pragma unroll 4
  for (int j = 0; j < 128; j++)
    acc += (double)r0[j] * (double)gate_W[j * 8 + e];
  G[((size_t)(d >> 1) * 64 + o) * 2 + (d & 1)] = acc;
  Gq[((size_t)(d >> 2) * 64 + o) * 4 + (d & 3)] = (float)acc;
  if (idx < 64) {
    double bacc = 0.0;
    for (int j = 0; j < 128; j++)
      bacc += (double)split_b[h * 128 + j] * (double)gate_W[j * 8 + e];
    gbias[idx] = bacc + (double)gate_b[e];
  }
}

// gate v12: fp32 main loop (Gq float4 layout, 1.25 LDS ops/k) +
// WAVE-COOPERATIVE fp64 fallback. r17-r19 diagnosis: the per-lane serial
// fallback (512 iter x ~10 dependent L2 loads at VGPR=64) costs ~400us for ANY
// wave that triggers once -- trigger RATE was irrelevant (v10 57% == v11 3% ==
// 240us; tail set by one wave). v12: __ballot ambiguous lanes; per trigger,
// all 64 lanes compute fp64 partials over k-slices (lane owns k=lane*16..+15,
// 8 iters x 8 experts, coalesced loads), butterfly __shfl_xor reduce, source
// lane takes result (~2us/trigger, 200x cheaper). Routing still exactly fp64
// for ambiguous tokens. Fused x->fp16 + hierarchical atomics.
__global__ __launch_bounds__(256) void gate_kernel(const float* __restrict__ x,
    const float* __restrict__ Gq, const f64x2* __restrict__ Gx2, const double* __restrict__ gbias,
    _Float16* __restrict__ x_h,
    float* __restrict__ tkw, int* __restrict__ lists, int* __restrict__ cnt) {
  __shared__ float Gsq[16 * 256];    // 16 KB: chunk (16 kquads x 64 cols x 4)
  __shared__ float xsf[16 * 68];     // 4.25 KB x chunk (fp32, stride 68)
  __shared__ float lg[16 * 64];      // 4 KB logits
  __shared__ int lcnt[8];
  __shared__ int lbase[8];
  int tid = threadIdx.x, lane = tid & 63, w = tid >> 6;
  int bs0 = blockIdx.x * 16;
  float accA[4], accB[4];
  #pragma unroll
  for (int r = 0; r < 4; r++) { accA[r] = 0.f; accB[r] = 0.f; }
  int xrow = tid >> 4, xc4 = tid & 15;
  const float* xr = xsf + (w * 4) * 68;
  if (tid < 8) lcnt[tid] = 0;

  for (int ch = 0; ch < 16; ch++) {
    __syncthreads();           // previous chunk's reads complete before overwrite
    // stage x chunk (16 rows x 64 k) + fused fp16 convert
    float4 xv4 = *(const float4*)(x + (size_t)(bs0 + xrow) * ND + ch * 64 + xc4 * 4);
    *(float4*)&xsf[xrow * 68 + xc4 * 4] = xv4;
    f16x4 xh = { (_Float16)xv4.x, (_Float16)xv4.y, (_Float16)xv4.z, (_Float16)xv4.w };
    *(f16x4*)(x_h + (size_t)(bs0 + xrow) * ND + ch * 64 + xc4 * 4) = xh;
    // async-stage Gq chunk (16 KB linear)
    #pragma unroll
    for (int j = 0; j < 4; j++) {
      int n = j * 256 + tid;           // 0..1023 16B granules
      gload_lds16(Gq + (size_t)ch * 4096 + n * 4, Gsq + n * 4);
    }
    __syncthreads();           // compiler drains vmcnt: G + x ready
    #pragma unroll 4
    for (int kq = 0; kq < 16; kq++) {
      float4 g = *(const float4*)&Gsq[kq * 256 + lane * 4];   // b128, coalesced LDS
      #pragma unroll
      for (int r = 0; r < 4; r++) {
        float4 xv = *(const float4*)(xr + r * 68 + kq * 4);   // b128 broadcast
        accA[r] = fmaf(xv.x, g.x, accA[r]);
        accB[r] = fmaf(xv.y, g.y, accB[r]);
        accA[r] = fmaf(xv.z, g.z, accA[r]);
        accB[r] = fmaf(xv.w, g.w, accB[r]);
      }
    }
  }
  float gbf = (float)gbias[lane];
  #pragma unroll
  for (int r = 0; r < 4; r++)
    lg[(w * 4 + r) * 64 + lane] = accA[r] + accB[r] + gbf;
  __syncthreads();

  int i1 = 0, i2 = 0, token = 0, p1 = 0, p2 = 0;
  if (tid < 128) {
    int row = tid >> 3, h = tid & 7;
    const float* L = lg + row * 64 + h * 8;
    float v1 = L[0];
    #pragma unroll
    for (int e2 = 1; e2 < 8; e2++) if (L[e2] > v1) { v1 = L[e2]; i1 = e2; }
    i2 = -1; float v2 = -1e30f;
    #pragma unroll
    for (int e2 = 0; e2 < 8; e2++) if (e2 != i1 && L[e2] > v2) { v2 = L[e2]; i2 = e2; }
    float v3 = -1e30f;
    #pragma unroll
    for (int e2 = 0; e2 < 8; e2++) if (e2 != i1 && e2 != i2 && L[e2] > v3) v3 = L[e2];
    float g1 = 0.f, g2 = 0.f;
    bool amb = !((v1 - v2 >= EPS_GATE) && (v2 - v3 >= EPS_GATE));
    if (!amb) {
      float ex = expf(v2 - v1);
      float den = 1.f + ex;
      g1 = 1.f / den; g2 = ex / den;
    }
    // wave-cooperative fp64 recompute for each ambiguous lane (rare)
    unsigned long long mask = __ballot(amb);
    while (mask) {
      int src = __ffsll((long long)mask) - 1;
      mask &= mask - 1;
      int srow = __shfl(row, src, 64);
      int sh   = __shfl(h, src, 64);
      double part[8];
      #pragma unroll
      for (int e2 = 0; e2 < 8; e2++) part[e2] = 0.0;
      const float* xg = x + (size_t)(bs0 + srow) * ND + lane * 16;
      #pragma unroll
      for (int kk = 0; kk < 8; kk++) {          // kp = lane*8 + kk
        double x0 = (double)xg[kk * 2], x1 = (double)xg[kk * 2 + 1];
        const f64x2* gp = Gx2 + (size_t)(lane * 8 + kk) * 64 + sh * 8;
        #pragma unroll
        for (int e2 = 0; e2 < 8; e2++) {
          f64x2 g = gp[e2];
          part[e2] += x0 * g.x + x1 * g.y;
        }
      }
      #pragma unroll
      for (int m = 1; m < 64; m <<= 1)
        #pragma unroll
        for (int e2 = 0; e2 < 8; e2++) part[e2] += __shfl_xor(part[e2], m, 64);
      if (lane == src) {
        double L64[8];
        #pragma unroll
        for (int e2 = 0; e2 < 8; e2++) L64[e2] = part[e2] + gbias[sh * 8 + e2];
        i1 = 0; double d1 = L64[0];
        #pragma unroll
        for (int e2 = 1; e2 < 8; e2++) if (L64[e2] > d1) { d1 = L64[e2]; i1 = e2; }
        i2 = -1; double d2 = -1e300;
        #pragma unroll
        for (int e2 = 0; e2 < 8; e2++) if (e2 != i1 && L64[e2] > d2) { d2 = L64[e2]; i2 = e2; }
        float ex = expf((float)(d2 - d1));
        float den = 1.f + ex;
        g1 = 1.f / den; g2 = ex / den;
      }
    }
    token = (bs0 + row) * 8 + h;
    tkw[token * 2]     = g1;
    tkw[token * 2 + 1] = g2;
    p1 = atomicAdd(&lcnt[i1], 1);             // LDS atomics: cheap
    p2 = atomicAdd(&lcnt[i2], 1);
  }
  __syncthreads();
  if (tid < 8) lbase[tid] = atomicAdd(cnt + tid * 64, lcnt[tid]);   // 8 global atomics/block
  __syncthreads();
  if (tid < 128) {
    lists[(size_t)i1 * NT + lbase[i1] + p1] = token * 2;
    lists[(size_t)i2 * NT + lbase[i2] + p2] = token * 2 + 1;
  }
}

// C[M][N] = A[M][K] @ Bt[N][K]^T + bias; fp16 inputs, fp32 acc.
// 128x128 tile, BK=32, 4 waves, global_load_lds w16, XCD-chunked swizzle (T1).
__global__ __launch_bounds__(256) void gemm_f16_kernel(
    const _Float16* __restrict__ A, const _Float16* __restrict__ Bt,
    const float* __restrict__ bias, float* __restrict__ Cf, _Float16* __restrict__ Ch,
    int M, int N, int Kd) {
  __shared__ _Float16 As[128 * 32];
  __shared__ _Float16 Bs[128 * 32];
  int tid = threadIdx.x, lane = tid & 63, w = tid >> 6;
  int wr = w >> 1, wc = w & 1;
  int lid = blockIdx.y * 8 + blockIdx.x;        // dispatch order (x fastest)
  int xcd = lid & 7, sub = (lid >> 3) & 7, grp = lid >> 6;
  int m0 = (xcd * 8 + sub) * 128;               // contiguous A-panels per XCD
  int n0 = grp * 128;
  f32x4 acc[4][4];
  #pragma unroll
  for (int i = 0; i < 4; i++)
    #pragma unroll
    for (int j = 0; j < 4; j++) acc[i][j] = (f32x4){0.f, 0.f, 0.f, 0.f};
  int srow = lane >> 2, scol = (lane & 3) * 8;
  int fr = lane & 15, ko = (lane >> 4) * 8;
  const _Float16* Ag = A + (size_t)(m0 + srow) * Kd + scol;
  const _Float16* Bg = Bt + (size_t)(n0 + srow) * Kd + scol;

  for (int k0 = 0; k0 < Kd; k0 += 32) {
    #pragma unroll
    for (int j = 0; j < 2; j++) {
      int rb = (w * 2 + j) * 16;
      gload_lds16(Ag + (size_t)rb * Kd + k0, As + rb * 32);
      gload_lds16(Bg + (size_t)rb * Kd + k0, Bs + rb * 32);
    }
    __syncthreads();
    f16x8 af[4], bq[4];
    #pragma unroll
    for (int mi = 0; mi < 4; mi++) af[mi] = *(const f16x8*)(As + (wr * 64 + mi * 16 + fr) * 32 + ko);
    #pragma unroll
    for (int ni = 0; ni < 4; ni++) bq[ni] = *(const f16x8*)(Bs + (wc * 64 + ni * 16 + fr) * 32 + ko);
    __syncthreads();
    #pragma unroll
    for (int mi = 0; mi < 4; mi++)
      #pragma unroll
      for (int ni = 0; ni < 4; ni++)
        acc[mi][ni] = __builtin_amdgcn_mfma_f32_16x16x32_f16(af[mi], bq[ni], acc[mi][ni], 0, 0, 0);
  }
  int rbase = m0 + wr * 64 + ((lane >> 4) << 2);
  int cbase = n0 + wc * 64 + (lane & 15);
  #pragma unroll
  for (int mi = 0; mi < 4; mi++)
    #pragma unroll
    for (int ni = 0; ni < 4; ni++) {
      int cc = cbase + ni * 16;
      float bv = bias ? bias[cc] : 0.f;
      #pragma unroll
      for (int r = 0; r < 4; r++) {
        int rr = rbase + mi * 16 + r;
        float v = acc[mi][ni][r] + bv;
        if (Cf) Cf[(size_t)rr * N + cc] = v;
        if (Ch) Ch[(size_t)rr * N + cc] = (_Float16)v;
      }
    }
}

// Grouped expert kernel v9 = v7 + swapped-operand phase A (acc1 = mfma(bq, af)
// computes h^T: reg-quad = 4 consecutive ff for one token -> single b64 h-write).
// 3-ring counted-vmcnt staging; phase B/epilogue as v7.
__global__ __launch_bounds__(512, 2) void expert_kernel(
    const _Float16* __restrict__ t_h, const _Float16* __restrict__ W1t, const _Float16* __restrict__ W2t,
    const float* __restrict__ b1, const float* __restrict__ b2,
    const int* __restrict__ cnt, const int* __restrict__ lists, const float* __restrict__ tkw,
    _Float16* __restrict__ slots) {
  int e = blockIdx.x & 7;              // consecutive blocks -> different XCDs
  int m0 = (blockIdx.x >> 3) * 128;
  int count = cnt[e * 64];
  if (m0 >= count) return;
  __shared__ _Float16 ring[3][64 * 128];  // 3 x 16 KB staging ring
  __shared__ _Float16 h_s[128 * 64];      // 16 KB [tok128][ff64] 128B rows
  __shared__ float b1s[NFF];              // 2 KB
  __shared__ float b2s[HD];               // 512 B
  __shared__ int alist[128];
  __shared__ float aw[128];
  int tid = threadIdx.x, lane = tid & 63, w = tid >> 6;
  int wr = w >> 1, wc = w & 1;         // 4 row-quarters (32) x 2 col-halves (64)
  int fr = lane & 15, g = lane >> 4;

  if (tid < 128) {
    int idx = m0 + tid;
    int a = (idx < count) ? lists[(size_t)e * NT + idx] : -1;
    alist[tid] = a;
    aw[tid] = (a >= 0) ? tkw[a] : 0.f;
  }
  b1s[tid] = b1[e * NFF + tid];
  if (tid < 128) b2s[tid] = b2[e * HD + tid];
  __syncthreads();

  auto stage = [&](int p) {
    if (p >= 16) return;
    int ch = p >> 1;
    _Float16* dst = &ring[p % 3][0];
    if ((p & 1) == 0) {
      #pragma unroll
      for (int j = 0; j < 2; j++) {
        int n = j * 512 + tid;           // 16 granules per 256B row
        int r = n >> 4, gg = n & 15;
        int sg = gg ^ ((r >> 1) & 7);
        gload_lds16(W1t + (size_t)e * (NFF * HD) + (size_t)(ch * 64 + r) * HD + sg * 8, dst + n * 8);
      }
    } else {
      #pragma unroll
      for (int j = 0; j < 2; j++) {
        int n = j * 512 + tid;           // 8 granules per 128B row
        int r = n >> 3, gg = n & 7;
        int sg = gg ^ ((r >> 1) & 7);
        gload_lds16(W2t + (size_t)e * (HD * NFF) + (size_t)r * NFF + ch * 64 + sg * 8, dst + n * 8);
      }
    }
  };

  // gather this wave's 32 token rows into registers (held across all phases)
  f16x8 af[2][4];
  #pragma unroll
  for (int mi = 0; mi < 2; mi++) {
    int rloc = wr * 32 + mi * 16 + fr;
    int a = alist[rloc];
    const _Float16* tb = t_h + (size_t)(a >> 1) * HD;
    #pragma unroll
    for (int ks = 0; ks < 4; ks++) {
      f16x8 v = {0, 0, 0, 0, 0, 0, 0, 0};
      if (a >= 0) v = *(const f16x8*)(tb + ks * 32 + g * 8);
      af[mi][ks] = v;
    }
  }
  asm volatile("s_waitcnt vmcnt(0)" ::: "memory");   // drain gather: loop vmcnt is stage-only
  stage(0); stage(1);
  asm volatile("s_waitcnt vmcnt(2) lgkmcnt(0)\n\ts_barrier" ::: "memory");  // stage(0) landed

  f32x4 acc2[2][4];
  #pragma unroll
  for (int i = 0; i < 2; i++)
    #pragma unroll
    for (int j = 0; j < 4; j++) acc2[i][j] = (f32x4){0.f, 0.f, 0.f, 0.f};

  #pragma unroll
  for (int p = 0; p < 16; p++) {
    stage(p + 2);
    int ch = p >> 1;
    const char* WB = (const char*)&ring[p % 3][0];
    if ((p & 1) == 0) {
      // ---- A (swapped): acc1 = W1^T . t^T = h^T; reg-quad = 4 consecutive ff ----
      float b1r[2][4];
      #pragma unroll
      for (int ni = 0; ni < 2; ni++)
        #pragma unroll
        for (int r = 0; r < 4; r++)
          b1r[ni][r] = b1s[ch * 64 + wc * 32 + ni * 16 + g * 4 + r];
      f32x4 acc1[2][2];    // [mi tok-block][ni ff-block]
      #pragma unroll
      for (int i = 0; i < 2; i++)
        #pragma unroll
        for (int j = 0; j < 2; j++) acc1[i][j] = (f32x4){0.f, 0.f, 0.f, 0.f};
      #pragma unroll
      for (int ks = 0; ks < 4; ks++) {
        f16x8 bq[2];
        #pragma unroll
        for (int ni = 0; ni < 2; ni++) {
          int rw = wc * 32 + ni * 16 + fr;       // ff row of chunk (0..63)
          int byte = rw * 256 + ((ks * 64 + g * 16) ^ (((rw >> 1) & 7) << 4));
          bq[ni] = *(const f16x8*)(WB + byte);
        }
        #pragma unroll
        for (int mi = 0; mi < 2; mi++)
          #pragma unroll
          for (int ni = 0; ni < 2; ni++)
            acc1[mi][ni] = __builtin_amdgcn_mfma_f32_16x16x32_f16(bq[ni], af[mi][ks], acc1[mi][ni], 0, 0, 0);
      }
      // relu + bias -> pack 4 consecutive ff -> single b64 write per (mi,ni)
      #pragma unroll
      for (int mi = 0; mi < 2; mi++)
        #pragma unroll
        for (int ni = 0; ni < 2; ni++) {
          f16x4 hv;
          #pragma unroll
          for (int r = 0; r < 4; r++)
            hv[r] = (_Float16)fmaxf(acc1[mi][ni][r] + b1r[ni][r], 0.f);
          int tok = wr * 32 + mi * 16 + fr;
          int foff = wc * 64 + ni * 32 + g * 8;       // ff*2 bytes
          int byte = tok * 128 + (foff ^ (((tok >> 1) & 7) << 4));
          *(f16x4*)((char*)h_s + byte) = hv;
        }
    } else {
      // ---- B: acc2 += h(:, ch) @ W2chunk ----
      #pragma unroll
      for (int ks = 0; ks < 2; ks++) {
        f16x8 ah[2], bq[4];
        #pragma unroll
        for (int mi = 0; mi < 2; mi++) {
          int row = wr * 32 + mi * 16 + fr;
          int byte = row * 128 + ((ks * 64 + g * 16) ^ (((row >> 1) & 7) << 4));
          ah[mi] = *(const f16x8*)((const char*)h_s + byte);
        }
        #pragma unroll
        for (int ni = 0; ni < 4; ni++) {
          int rw = wc * 64 + ni * 16 + fr;       // d row (0..127)
          int byte = rw * 128 + ((ks * 64 + g * 16) ^ (((rw >> 1) & 7) << 4));
          bq[ni] = *(const f16x8*)((const char*)&ring[p % 3][0] + byte);
        }
        #pragma unroll
        for (int mi = 0; mi < 2; mi++)
          #pragma unroll
          for (int ni = 0; ni < 4; ni++)
            acc2[mi][ni] = __builtin_amdgcn_mfma_f32_16x16x32_f16(ah[mi], bq[ni], acc2[mi][ni], 0, 0, 0);
      }
    }
    if (p == 14) {
      asm volatile("s_waitcnt vmcnt(0) lgkmcnt(0)\n\ts_barrier" ::: "memory");
    } else if (p < 14) {
      asm volatile("s_waitcnt vmcnt(2) lgkmcnt(0)\n\ts_barrier" ::: "memory");
    }
  }
  // epilogue: gate-scale + fp16 scatter to slots
  #pragma unroll
  for (int mi = 0; mi < 2; mi++)
    #pragma unroll
    for (int ni = 0; ni < 4; ni++) {
      int ncol = wc * 64 + ni * 16 + fr;
      float bv = b2s[ncol];
      #pragma unroll
      for (int r = 0; r < 4; r++) {
        int m = wr * 32 + mi * 16 + g * 4 + r;
        int a = alist[m];
        if (a >= 0)
          slots[(size_t)a * HD + ncol] = (_Float16)(aw[m] * (acc2[mi][ni][r] + bv));
      }
    }
}

// combine slots -> momentum update -> residual -> LayerNorm
__global__ __launch_bounds__(256) void combine_ln_kernel(
    const _Float16* __restrict__ slots, const float* __restrict__ momentum,
    const _Float16* __restrict__ t_h, const float* __restrict__ ln_g, const float* __restrict__ ln_b,
    float* __restrict__ nm_out, _Float16* __restrict__ out_h) {
  int w = threadIdx.x >> 6, lane = threadIdx.x & 63;
  int tok = blockIdx.x * 4 + w;
  int d0 = lane * 2;
  f16x2 s0 = *(const f16x2*)(slots + (size_t)tok * 256 + d0);
  f16x2 s1 = *(const f16x2*)(slots + (size_t)tok * 256 + 128 + d0);
  float2 mo = *(const float2*)(momentum + (size_t)tok * HD + d0);
  f16x2 tv = *(const f16x2*)(t_h + (size_t)tok * HD + d0);
  float nm0 = -((float)s0.x + (float)s1.x) + MU_F * mo.x;
  float nm1 = -((float)s0.y + (float)s1.y) + MU_F * mo.y;
  float2 nm2; nm2.x = nm0; nm2.y = nm1;
  *(float2*)(nm_out + (size_t)tok * HD + d0) = nm2;
  float r0 = (float)tv.x + nm0;
  float r1 = (float)tv.y + nm1;
  float s = r0 + r1, sq = r0 * r0 + r1 * r1;
  #pragma unroll
  for (int m = 1; m < 64; m <<= 1) { s += __shfl_xor(s, m, 64); sq += __shfl_xor(sq, m, 64); }
  float mean = s * (1.f / 128.f);
  float var = sq * (1.f / 128.f) - mean * mean;
  float is = rsqrtf(var + LN_EPS_F);
  float y0 = (r0 - mean) * is * ln_g[d0] + ln_b[d0];
  float y1 = (r1 - mean) * is * ln_g[d0 + 1] + ln_b[d0 + 1];
  f16x2 yo = { (_Float16)y0, (_Float16)y1 };
  *(f16x2*)(out_h + (size_t)tok * HD + d0) = yo;
}

extern "C" void kernel_launch(void* const* d_in, const int* in_sizes, int n_in,
                              void* d_out, int out_size, void* d_ws, size_t ws_size,
                              hipStream_t stream) {
  const float* x        = (const float*)d_in[0];
  const float* momentum = (const float*)d_in[1];
  const float* split_W  = (const float*)d_in[2];
  const float* split_b  = (const float*)d_in[3];
  const float* gate_W   = (const float*)d_in[4];
  const float* gate_b   = (const float*)d_in[5];
  const float* W1       = (const float*)d_in[6];
  const float* b1       = (const float*)d_in[7];
  const float* W2       = (const float*)d_in[8];
  const float* b2       = (const float*)d_in[9];
  const float* ln_g     = (const float*)d_in[10];
  const float* ln_b     = (const float*)d_in[11];
  const float* merge_W  = (const float*)d_in[12];
  const float* merge_b  = (const float*)d_in[13];
  float* final_out = (float*)d_out;
  float* nm_out    = final_out + (size_t)NBS * ND;

  char* ws = (char*)d_ws;
  size_t off = 0;
  auto alloc = [&](size_t bytes) { void* p = ws + off; off = (off + bytes + 255) & ~(size_t)255; return p; };
  _Float16* x_h   = (_Float16*)alloc((size_t)NBS * ND * 2);
  _Float16* t_h   = (_Float16*)alloc((size_t)NT * HD * 2);
  _Float16* out_h = (_Float16*)alloc((size_t)NT * HD * 2);
  _Float16* sWt   = (_Float16*)alloc((size_t)ND * ND * 2);
  _Float16* mWt   = (_Float16*)alloc((size_t)ND * ND * 2);
  _Float16* W1t   = (_Float16*)alloc((size_t)NE * HD * NFF * 2);
  _Float16* W2t   = (_Float16*)alloc((size_t)NE * HD * NFF * 2);
  f64x2*    Gx2   = (f64x2*)alloc((size_t)512 * 64 * 16);
  float*    Gq    = (float*)alloc((size_t)512 * 64 * 8);
  double*   gbias = (double*)alloc(64 * 8);
  float*    tkw   = (float*)alloc((size_t)NT * 2 * 4);
  int*      lists = (int*)alloc((size_t)NE * NT * 4);
  int*      cnt   = (int*)alloc(512 * 4);
  _Float16* slots = (_Float16*)alloc((size_t)NT * 2 * HD * 2);
  (void)in_sizes; (void)n_in; (void)out_size; (void)ws_size;

  tr_cvt_all_kernel<<<3072, dim3(32, 8), 0, stream>>>(split_W, merge_W, W1, W2, sWt, mWt, W1t, W2t);
  build_G_kernel<<<256, 256, 0, stream>>>(split_W, split_b, gate_W, gate_b, (double*)Gx2, Gq, gbias, cnt);
  // gate also produces x_h (fused convert), so it runs before the split GEMM
  gate_kernel<<<512, 256, 0, stream>>>(x, Gq, Gx2, gbias, x_h, tkw, lists, cnt);
  // t = x @ split_W + split_b   (fp16 out for downstream MFMA)
  gemm_f16_kernel<<<dim3(8, 64), 256, 0, stream>>>(x_h, sWt, split_b, nullptr, t_h, NBS, ND, ND);
  expert_kernel<<<NE * 512, 512, 0, stream>>>(t_h, W1t, W2t, b1, b2, cnt, lists, tkw, slots);
  combine_ln_kernel<<<NT / 4, 256, 0, stream>>>(slots, momentum, t_h, ln_g, ln_b, nm_out, out_h);
  // final = out @ merge_W + merge_b
  gemm_f16_kernel<<<dim3(8, 64), 256, 0, stream>>>(out_h, mWt, merge_b, final_out, nullptr, NBS, ND, ND);
}

// Round 21
// 206.889 us; speedup vs baseline: 1.9374x; 1.0650x over previous
//
#include <hip/hip_runtime.h>

#define NBATCH 4
#define NS 2048
#define ND 1024
#define NH 8
#define HD 128
#define NFF 512
#define NE 8
#define NT 65536       /* B*S*H tokens */
#define NBS 8192       /* B*S rows */
#define MU_F 0.7f
#define LN_EPS_F 1e-5f
#define EPS_GATE 1e-4f

typedef __attribute__((ext_vector_type(4))) float f32x4;
typedef __attribute__((ext_vector_type(2))) double f64x2;
typedef __attribute__((ext_vector_type(8))) _Float16 f16x8;
typedef __attribute__((ext_vector_type(4))) _Float16 f16x4;
typedef __attribute__((ext_vector_type(2))) _Float16 f16x2;

__device__ __forceinline__ void gload_lds16(const void* g, void* l) {
  __builtin_amdgcn_global_load_lds(
      (const __attribute__((address_space(1))) unsigned int*)g,
      (__attribute__((address_space(3))) unsigned int*)l, 16, 0, 0);
}

// prep: 4 weight transposes (blocks 0..3071) + build_G (blocks 3072..3327)
// fused into ONE launch so build_G's 256 blocks overlap the transpose work.
__global__ void prep_kernel(const float* __restrict__ split_W, const float* __restrict__ merge_W,
                            const float* __restrict__ W1, const float* __restrict__ W2,
                            const float* __restrict__ split_b, const float* __restrict__ gate_W,
                            const float* __restrict__ gate_b,
                            _Float16* __restrict__ sWt, _Float16* __restrict__ mWt,
                            _Float16* __restrict__ W1t, _Float16* __restrict__ W2t,
                            double* __restrict__ G, float* __restrict__ Gq,
                            double* __restrict__ gbias, int* __restrict__ cnt) {
  int id = blockIdx.x;
  if (id >= 3072) {
    // ---- build_G part: one thread per G[d][o] scalar ----
    int tid = threadIdx.y * 32 + threadIdx.x;
    int idx = (id - 3072) * 256 + tid;   // = d*64 + o
    if (id == 3072) { cnt[tid] = 0; cnt[tid + 256] = 0; }
    int d = idx >> 6, o = idx & 63, h = o >> 3, e = o & 7;
    double acc = 0.0;
    const float* r0 = split_W + (size_t)d * ND + h * 128;
    #pragma unroll 4
    for (int j = 0; j < 128; j++)
      acc += (double)r0[j] * (double)gate_W[j * 8 + e];
    G[((size_t)(d >> 1) * 64 + o) * 2 + (d & 1)] = acc;
    Gq[((size_t)(d >> 2) * 64 + o) * 4 + (d & 3)] = (float)acc;
    if (idx < 64) {
      double bacc = 0.0;
      for (int j = 0; j < 128; j++)
        bacc += (double)split_b[h * 128 + j] * (double)gate_W[j * 8 + e];
      gbias[idx] = bacc + (double)gate_b[e];
    }
    return;
  }
  // ---- transpose part ----
  __shared__ float tile[32][33];
  const float* in; _Float16* out; int R, C, bx, by, b;
  if (id < 1024)      { in = split_W; out = sWt; R = ND;  C = ND;  bx = id & 31; by = id >> 5; b = 0; }
  else if (id < 2048) { id -= 1024; in = merge_W; out = mWt; R = ND;  C = ND;  bx = id & 31; by = id >> 5; b = 0; }
  else if (id < 2560) { id -= 2048; in = W1; out = W1t; R = HD;  C = NFF; bx = id & 15; by = (id >> 4) & 3; b = id >> 6; }
  else                { id -= 2560; in = W2; out = W2t; R = NFF; C = HD;  bx = id & 3;  by = (id >> 2) & 15; b = id >> 6; }
  const float* inp = in + (size_t)b * R * C;
  _Float16* outp = out + (size_t)b * R * C;
  int c = bx * 32 + threadIdx.x;
  int r0 = by * 32;
  #pragma unroll
  for (int i = 0; i < 4; i++) {
    int r = r0 + threadIdx.y + i * 8;
    tile[threadIdx.y + i * 8][threadIdx.x] = inp[(size_t)r * C + c];
  }
  __syncthreads();
  int rr = r0 + threadIdx.x;
  #pragma unroll
  for (int i = 0; i < 4; i++) {
    int cc = bx * 32 + threadIdx.y + i * 8;
    outp[(size_t)cc * R + rr] = (_Float16)tile[threadIdx.x][threadIdx.y + i * 8];
  }
}

// gate v12 (proven r20): fp32 main loop (Gq float4 layout) + wave-cooperative
// fp64 fallback at EPS=1e-4. Fused x->fp16 + hierarchical atomics.
__global__ __launch_bounds__(256) void gate_kernel(const float* __restrict__ x,
    const float* __restrict__ Gq, const f64x2* __restrict__ Gx2, const double* __restrict__ gbias,
    _Float16* __restrict__ x_h,
    float* __restrict__ tkw, int* __restrict__ lists, int* __restrict__ cnt) {
  __shared__ float Gsq[16 * 256];    // 16 KB: chunk (16 kquads x 64 cols x 4)
  __shared__ float xsf[16 * 68];     // 4.25 KB x chunk (fp32, stride 68)
  __shared__ float lg[16 * 64];      // 4 KB logits
  __shared__ int lcnt[8];
  __shared__ int lbase[8];
  int tid = threadIdx.x, lane = tid & 63, w = tid >> 6;
  int bs0 = blockIdx.x * 16;
  float accA[4], accB[4];
  #pragma unroll
  for (int r = 0; r < 4; r++) { accA[r] = 0.f; accB[r] = 0.f; }
  int xrow = tid >> 4, xc4 = tid & 15;
  const float* xr = xsf + (w * 4) * 68;
  if (tid < 8) lcnt[tid] = 0;

  for (int ch = 0; ch < 16; ch++) {
    __syncthreads();           // previous chunk's reads complete before overwrite
    float4 xv4 = *(const float4*)(x + (size_t)(bs0 + xrow) * ND + ch * 64 + xc4 * 4);
    *(float4*)&xsf[xrow * 68 + xc4 * 4] = xv4;
    f16x4 xh = { (_Float16)xv4.x, (_Float16)xv4.y, (_Float16)xv4.z, (_Float16)xv4.w };
    *(f16x4*)(x_h + (size_t)(bs0 + xrow) * ND + ch * 64 + xc4 * 4) = xh;
    #pragma unroll
    for (int j = 0; j < 4; j++) {
      int n = j * 256 + tid;           // 0..1023 16B granules
      gload_lds16(Gq + (size_t)ch * 4096 + n * 4, Gsq + n * 4);
    }
    __syncthreads();           // compiler drains vmcnt: G + x ready
    #pragma unroll 4
    for (int kq = 0; kq < 16; kq++) {
      float4 g = *(const float4*)&Gsq[kq * 256 + lane * 4];   // b128, coalesced LDS
      #pragma unroll
      for (int r = 0; r < 4; r++) {
        float4 xv = *(const float4*)(xr + r * 68 + kq * 4);   // b128 broadcast
        accA[r] = fmaf(xv.x, g.x, accA[r]);
        accB[r] = fmaf(xv.y, g.y, accB[r]);
        accA[r] = fmaf(xv.z, g.z, accA[r]);
        accB[r] = fmaf(xv.w, g.w, accB[r]);
      }
    }
  }
  float gbf = (float)gbias[lane];
  #pragma unroll
  for (int r = 0; r < 4; r++)
    lg[(w * 4 + r) * 64 + lane] = accA[r] + accB[r] + gbf;
  __syncthreads();

  int i1 = 0, i2 = 0, token = 0, p1 = 0, p2 = 0;
  if (tid < 128) {
    int row = tid >> 3, h = tid & 7;
    const float* L = lg + row * 64 + h * 8;
    float v1 = L[0];
    #pragma unroll
    for (int e2 = 1; e2 < 8; e2++) if (L[e2] > v1) { v1 = L[e2]; i1 = e2; }
    i2 = -1; float v2 = -1e30f;
    #pragma unroll
    for (int e2 = 0; e2 < 8; e2++) if (e2 != i1 && L[e2] > v2) { v2 = L[e2]; i2 = e2; }
    float v3 = -1e30f;
    #pragma unroll
    for (int e2 = 0; e2 < 8; e2++) if (e2 != i1 && e2 != i2 && L[e2] > v3) v3 = L[e2];
    float g1 = 0.f, g2 = 0.f;
    bool amb = !((v1 - v2 >= EPS_GATE) && (v2 - v3 >= EPS_GATE));
    if (!amb) {
      float ex = expf(v2 - v1);
      float den = 1.f + ex;
      g1 = 1.f / den; g2 = ex / den;
    }
    // wave-cooperative fp64 recompute for each ambiguous lane (rare)
    unsigned long long mask = __ballot(amb);
    while (mask) {
      int src = __ffsll((long long)mask) - 1;
      mask &= mask - 1;
      int srow = __shfl(row, src, 64);
      int sh   = __shfl(h, src, 64);
      double part[8];
      #pragma unroll
      for (int e2 = 0; e2 < 8; e2++) part[e2] = 0.0;
      const float* xg = x + (size_t)(bs0 + srow) * ND + lane * 16;
      #pragma unroll
      for (int kk = 0; kk < 8; kk++) {          // kp = lane*8 + kk
        double x0 = (double)xg[kk * 2], x1 = (double)xg[kk * 2 + 1];
        const f64x2* gp = Gx2 + (size_t)(lane * 8 + kk) * 64 + sh * 8;
        #pragma unroll
        for (int e2 = 0; e2 < 8; e2++) {
          f64x2 g = gp[e2];
          part[e2] += x0 * g.x + x1 * g.y;
        }
      }
      #pragma unroll
      for (int m = 1; m < 64; m <<= 1)
        #pragma unroll
        for (int e2 = 0; e2 < 8; e2++) part[e2] += __shfl_xor(part[e2], m, 64);
      if (lane == src) {
        double L64[8];
        #pragma unroll
        for (int e2 = 0; e2 < 8; e2++) L64[e2] = part[e2] + gbias[sh * 8 + e2];
        i1 = 0; double d1 = L64[0];
        #pragma unroll
        for (int e2 = 1; e2 < 8; e2++) if (L64[e2] > d1) { d1 = L64[e2]; i1 = e2; }
        i2 = -1; double d2 = -1e300;
        #pragma unroll
        for (int e2 = 0; e2 < 8; e2++) if (e2 != i1 && L64[e2] > d2) { d2 = L64[e2]; i2 = e2; }
        float ex = expf((float)(d2 - d1));
        float den = 1.f + ex;
        g1 = 1.f / den; g2 = ex / den;
      }
    }
    token = (bs0 + row) * 8 + h;
    tkw[token * 2]     = g1;
    tkw[token * 2 + 1] = g2;
    p1 = atomicAdd(&lcnt[i1], 1);             // LDS atomics: cheap
    p2 = atomicAdd(&lcnt[i2], 1);
  }
  __syncthreads();
  if (tid < 8) lbase[tid] = atomicAdd(cnt + tid * 64, lcnt[tid]);   // 8 global atomics/block
  __syncthreads();
  if (tid < 128) {
    lists[(size_t)i1 * NT + lbase[i1] + p1] = token * 2;
    lists[(size_t)i2 * NT + lbase[i2] + p2] = token * 2 + 1;
  }
}

// C[M][N] = A[M][K] @ Bt[N][K]^T + bias; fp16 inputs, fp32 acc.
// v3: BK=64 (2 MFMA K-halves per stage+barrier pair -> barrier count halves)
// with expert-proven XOR swizzle on the 128B-row LDS tiles: stage source
// pre-swizzled sg = gg^((r>>1)&7) (linear gload dest, rule 21); b128 fragment
// reads XOR the same key -> uniform 8 lanes/bank-quad (b128 floor).
// XCD-chunked block swizzle (T1) kept.
__global__ __launch_bounds__(256) void gemm_f16_kernel(
    const _Float16* __restrict__ A, const _Float16* __restrict__ Bt,
    const float* __restrict__ bias, float* __restrict__ Cf, _Float16* __restrict__ Ch,
    int M, int N, int Kd) {
  __shared__ _Float16 As[128 * 64];   // 16 KB, 128B rows, swizzled
  __shared__ _Float16 Bs[128 * 64];
  int tid = threadIdx.x, lane = tid & 63, w = tid >> 6;
  int wr = w >> 1, wc = w & 1;
  int lid = blockIdx.y * 8 + blockIdx.x;        // dispatch order (x fastest)
  int xcd = lid & 7, sub = (lid >> 3) & 7, grp = lid >> 6;
  int m0 = (xcd * 8 + sub) * 128;               // contiguous A-panels per XCD
  int n0 = grp * 128;
  f32x4 acc[4][4];
  #pragma unroll
  for (int i = 0; i < 4; i++)
    #pragma unroll
    for (int j = 0; j < 4; j++) acc[i][j] = (f32x4){0.f, 0.f, 0.f, 0.f};
  int fr = lane & 15, ko = lane >> 4;           // frag row, k-granule 0..3

  for (int k0 = 0; k0 < Kd; k0 += 64) {
    #pragma unroll
    for (int j = 0; j < 4; j++) {
      int n = j * 256 + tid;                    // 0..1023 granules (8 per row)
      int r = n >> 3, gg = n & 7;
      int sg = gg ^ ((r >> 1) & 7);
      gload_lds16(A + (size_t)(m0 + r) * Kd + k0 + sg * 8, As + n * 8);
      gload_lds16(Bt + (size_t)(n0 + r) * Kd + k0 + sg * 8, Bs + n * 8);
    }
    __syncthreads();
    #pragma unroll
    for (int kh = 0; kh < 2; kh++) {
      f16x8 af[4], bq[4];
      #pragma unroll
      for (int mi = 0; mi < 4; mi++) {
        int row = wr * 64 + mi * 16 + fr;
        int byte = row * 128 + ((kh * 64 + ko * 16) ^ (((row >> 1) & 7) << 4));
        af[mi] = *(const f16x8*)((const char*)As + byte);
      }
      #pragma unroll
      for (int ni = 0; ni < 4; ni++) {
        int row = wc * 64 + ni * 16 + fr;
        int byte = row * 128 + ((kh * 64 + ko * 16) ^ (((row >> 1) & 7) << 4));
        bq[ni] = *(const f16x8*)((const char*)Bs + byte);
      }
      #pragma unroll
      for (int mi = 0; mi < 4; mi++)
        #pragma unroll
        for (int ni = 0; ni < 4; ni++)
          acc[mi][ni] = __builtin_amdgcn_mfma_f32_16x16x32_f16(af[mi], bq[ni], acc[mi][ni], 0, 0, 0);
    }
    __syncthreads();
  }
  int rbase = m0 + wr * 64 + ((lane >> 4) << 2);
  int cbase = n0 + wc * 64 + (lane & 15);
  #pragma unroll
  for (int mi = 0; mi < 4; mi++)
    #pragma unroll
    for (int ni = 0; ni < 4; ni++) {
      int cc = cbase + ni * 16;
      float bv = bias ? bias[cc] : 0.f;
      #pragma unroll
      for (int r = 0; r < 4; r++) {
        int rr = rbase + mi * 16 + r;
        float v = acc[mi][ni][r] + bv;
        if (Cf) Cf[(size_t)rr * N + cc] = v;
        if (Ch) Ch[(size_t)rr * N + cc] = (_Float16)v;
      }
    }
}

// Grouped expert kernel v9 (proven): swapped-operand phase A (h^T -> single b64
// h-write), 3-ring counted-vmcnt staging, XCD expert pinning, fp16 slots.
__global__ __launch_bounds__(512, 2) void expert_kernel(
    const _Float16* __restrict__ t_h, const _Float16* __restrict__ W1t, const _Float16* __restrict__ W2t,
    const float* __restrict__ b1, const float* __restrict__ b2,
    const int* __restrict__ cnt, const int* __restrict__ lists, const float* __restrict__ tkw,
    _Float16* __restrict__ slots) {
  int e = blockIdx.x & 7;              // consecutive blocks -> different XCDs
  int m0 = (blockIdx.x >> 3) * 128;
  int count = cnt[e * 64];
  if (m0 >= count) return;
  __shared__ _Float16 ring[3][64 * 128];  // 3 x 16 KB staging ring
  __shared__ _Float16 h_s[128 * 64];      // 16 KB [tok128][ff64] 128B rows
  __shared__ float b1s[NFF];              // 2 KB
  __shared__ float b2s[HD];               // 512 B
  __shared__ int alist[128];
  __shared__ float aw[128];
  int tid = threadIdx.x, lane = tid & 63, w = tid >> 6;
  int wr = w >> 1, wc = w & 1;         // 4 row-quarters (32) x 2 col-halves (64)
  int fr = lane & 15, g = lane >> 4;

  if (tid < 128) {
    int idx = m0 + tid;
    int a = (idx < count) ? lists[(size_t)e * NT + idx] : -1;
    alist[tid] = a;
    aw[tid] = (a >= 0) ? tkw[a] : 0.f;
  }
  b1s[tid] = b1[e * NFF + tid];
  if (tid < 128) b2s[tid] = b2[e * HD + tid];
  __syncthreads();

  auto stage = [&](int p) {
    if (p >= 16) return;
    int ch = p >> 1;
    _Float16* dst = &ring[p % 3][0];
    if ((p & 1) == 0) {
      #pragma unroll
      for (int j = 0; j < 2; j++) {
        int n = j * 512 + tid;           // 16 granules per 256B row
        int r = n >> 4, gg = n & 15;
        int sg = gg ^ ((r >> 1) & 7);
        gload_lds16(W1t + (size_t)e * (NFF * HD) + (size_t)(ch * 64 + r) * HD + sg * 8, dst + n * 8);
      }
    } else {
      #pragma unroll
      for (int j = 0; j < 2; j++) {
        int n = j * 512 + tid;           // 8 granules per 128B row
        int r = n >> 3, gg = n & 7;
        int sg = gg ^ ((r >> 1) & 7);
        gload_lds16(W2t + (size_t)e * (HD * NFF) + (size_t)r * NFF + ch * 64 + sg * 8, dst + n * 8);
      }
    }
  };

  // gather this wave's 32 token rows into registers (held across all phases)
  f16x8 af[2][4];
  #pragma unroll
  for (int mi = 0; mi < 2; mi++) {
    int rloc = wr * 32 + mi * 16 + fr;
    int a = alist[rloc];
    const _Float16* tb = t_h + (size_t)(a >> 1) * HD;
    #pragma unroll
    for (int ks = 0; ks < 4; ks++) {
      f16x8 v = {0, 0, 0, 0, 0, 0, 0, 0};
      if (a >= 0) v = *(const f16x8*)(tb + ks * 32 + g * 8);
      af[mi][ks] = v;
    }
  }
  asm volatile("s_waitcnt vmcnt(0)" ::: "memory");   // drain gather: loop vmcnt is stage-only
  stage(0); stage(1);
  asm volatile("s_waitcnt vmcnt(2) lgkmcnt(0)\n\ts_barrier" ::: "memory");  // stage(0) landed

  f32x4 acc2[2][4];
  #pragma unroll
  for (int i = 0; i < 2; i++)
    #pragma unroll
    for (int j = 0; j < 4; j++) acc2[i][j] = (f32x4){0.f, 0.f, 0.f, 0.f};

  #pragma unroll
  for (int p = 0; p < 16; p++) {
    stage(p + 2);
    int ch = p >> 1;
    const char* WB = (const char*)&ring[p % 3][0];
    if ((p & 1) == 0) {
      // ---- A (swapped): acc1 = W1^T . t^T = h^T; reg-quad = 4 consecutive ff ----
      float b1r[2][4];
      #pragma unroll
      for (int ni = 0; ni < 2; ni++)
        #pragma unroll
        for (int r = 0; r < 4; r++)
          b1r[ni][r] = b1s[ch * 64 + wc * 32 + ni * 16 + g * 4 + r];
      f32x4 acc1[2][2];    // [mi tok-block][ni ff-block]
      #pragma unroll
      for (int i = 0; i < 2; i++)
        #pragma unroll
        for (int j = 0; j < 2; j++) acc1[i][j] = (f32x4){0.f, 0.f, 0.f, 0.f};
      #pragma unroll
      for (int ks = 0; ks < 4; ks++) {
        f16x8 bq[2];
        #pragma unroll
        for (int ni = 0; ni < 2; ni++) {
          int rw = wc * 32 + ni * 16 + fr;       // ff row of chunk (0..63)
          int byte = rw * 256 + ((ks * 64 + g * 16) ^ (((rw >> 1) & 7) << 4));
          bq[ni] = *(const f16x8*)(WB + byte);
        }
        #pragma unroll
        for (int mi = 0; mi < 2; mi++)
          #pragma unroll
          for (int ni = 0; ni < 2; ni++)
            acc1[mi][ni] = __builtin_amdgcn_mfma_f32_16x16x32_f16(bq[ni], af[mi][ks], acc1[mi][ni], 0, 0, 0);
      }
      // relu + bias -> pack 4 consecutive ff -> single b64 write per (mi,ni)
      #pragma unroll
      for (int mi = 0; mi < 2; mi++)
        #pragma unroll
        for (int ni = 0; ni < 2; ni++) {
          f16x4 hv;
          #pragma unroll
          for (int r = 0; r < 4; r++)
            hv[r] = (_Float16)fmaxf(acc1[mi][ni][r] + b1r[ni][r], 0.f);
          int tok = wr * 32 + mi * 16 + fr;
          int foff = wc * 64 + ni * 32 + g * 8;       // ff*2 bytes
          int byte = tok * 128 + (foff ^ (((tok >> 1) & 7) << 4));
          *(f16x4*)((char*)h_s + byte) = hv;
        }
    } else {
      // ---- B: acc2 += h(:, ch) @ W2chunk ----
      #pragma unroll
      for (int ks = 0; ks < 2; ks++) {
        f16x8 ah[2], bq[4];
        #pragma unroll
        for (int mi = 0; mi < 2; mi++) {
          int row = wr * 32 + mi * 16 + fr;
          int byte = row * 128 + ((ks * 64 + g * 16) ^ (((row >> 1) & 7) << 4));
          ah[mi] = *(const f16x8*)((const char*)h_s + byte);
        }
        #pragma unroll
        for (int ni = 0; ni < 4; ni++) {
          int rw = wc * 64 + ni * 16 + fr;       // d row (0..127)
          int byte = rw * 128 + ((ks * 64 + g * 16) ^ (((rw >> 1) & 7) << 4));
          bq[ni] = *(const f16x8*)((const char*)&ring[p % 3][0] + byte);
        }
        #pragma unroll
        for (int mi = 0; mi < 2; mi++)
          #pragma unroll
          for (int ni = 0; ni < 4; ni++)
            acc2[mi][ni] = __builtin_amdgcn_mfma_f32_16x16x32_f16(ah[mi], bq[ni], acc2[mi][ni], 0, 0, 0);
      }
    }
    if (p == 14) {
      asm volatile("s_waitcnt vmcnt(0) lgkmcnt(0)\n\ts_barrier" ::: "memory");
    } else if (p < 14) {
      asm volatile("s_waitcnt vmcnt(2) lgkmcnt(0)\n\ts_barrier" ::: "memory");
    }
  }
  // epilogue: gate-scale + fp16 scatter to slots
  #pragma unroll
  for (int mi = 0; mi < 2; mi++)
    #pragma unroll
    for (int ni = 0; ni < 4; ni++) {
      int ncol = wc * 64 + ni * 16 + fr;
      float bv = b2s[ncol];
      #pragma unroll
      for (int r = 0; r < 4; r++) {
        int m = wr * 32 + mi * 16 + g * 4 + r;
        int a = alist[m];
        if (a >= 0)
          slots[(size_t)a * HD + ncol] = (_Float16)(aw[m] * (acc2[mi][ni][r] + bv));
      }
    }
}

// combine slots -> momentum update -> residual -> LayerNorm
__global__ __launch_bounds__(256) void combine_ln_kernel(
    const _Float16* __restrict__ slots, const float* __restrict__ momentum,
    const _Float16* __restrict__ t_h, const float* __restrict__ ln_g, const float* __restrict__ ln_b,
    float* __restrict__ nm_out, _Float16* __restrict__ out_h) {
  int w = threadIdx.x >> 6, lane = threadIdx.x & 63;
  int tok = blockIdx.x * 4 + w;
  int d0 = lane * 2;
  f16x2 s0 = *(const f16x2*)(slots + (size_t)tok * 256 + d0);
  f16x2 s1 = *(const f16x2*)(slots + (size_t)tok * 256 + 128 + d0);
  float2 mo = *(const float2*)(momentum + (size_t)tok * HD + d0);
  f16x2 tv = *(const f16x2*)(t_h + (size_t)tok * HD + d0);
  float nm0 = -((float)s0.x + (float)s1.x) + MU_F * mo.x;
  float nm1 = -((float)s0.y + (float)s1.y) + MU_F * mo.y;
  float2 nm2; nm2.x = nm0; nm2.y = nm1;
  *(float2*)(nm_out + (size_t)tok * HD + d0) = nm2;
  float r0 = (float)tv.x + nm0;
  float r1 = (float)tv.y + nm1;
  float s = r0 + r1, sq = r0 * r0 + r1 * r1;
  #pragma unroll
  for (int m = 1; m < 64; m <<= 1) { s += __shfl_xor(s, m, 64); sq += __shfl_xor(sq, m, 64); }
  float mean = s * (1.f / 128.f);
  float var = sq * (1.f / 128.f) - mean * mean;
  float is = rsqrtf(var + LN_EPS_F);
  float y0 = (r0 - mean) * is * ln_g[d0] + ln_b[d0];
  float y1 = (r1 - mean) * is * ln_g[d0 + 1] + ln_b[d0 + 1];
  f16x2 yo = { (_Float16)y0, (_Float16)y1 };
  *(f16x2*)(out_h + (size_t)tok * HD + d0) = yo;
}

extern "C" void kernel_launch(void* const* d_in, const int* in_sizes, int n_in,
                              void* d_out, int out_size, void* d_ws, size_t ws_size,
                              hipStream_t stream) {
  const float* x        = (const float*)d_in[0];
  const float* momentum = (const float*)d_in[1];
  const float* split_W  = (const float*)d_in[2];
  const float* split_b  = (const float*)d_in[3];
  const float* gate_W   = (const float*)d_in[4];
  const float* gate_b   = (const float*)d_in[5];
  const float* W1       = (const float*)d_in[6];
  const float* b1       = (const float*)d_in[7];
  const float* W2       = (const float*)d_in[8];
  const float* b2       = (const float*)d_in[9];
  const float* ln_g     = (const float*)d_in[10];
  const float* ln_b     = (const float*)d_in[11];
  const float* merge_W  = (const float*)d_in[12];
  const float* merge_b  = (const float*)d_in[13];
  float* final_out = (float*)d_out;
  float* nm_out    = final_out + (size_t)NBS * ND;

  char* ws = (char*)d_ws;
  size_t off = 0;
  auto alloc = [&](size_t bytes) { void* p = ws + off; off = (off + bytes + 255) & ~(size_t)255; return p; };
  _Float16* x_h   = (_Float16*)alloc((size_t)NBS * ND * 2);
  _Float16* t_h   = (_Float16*)alloc((size_t)NT * HD * 2);
  _Float16* out_h = (_Float16*)alloc((size_t)NT * HD * 2);
  _Float16* sWt   = (_Float16*)alloc((size_t)ND * ND * 2);
  _Float16* mWt   = (_Float16*)alloc((size_t)ND * ND * 2);
  _Float16* W1t   = (_Float16*)alloc((size_t)NE * HD * NFF * 2);
  _Float16* W2t   = (_Float16*)alloc((size_t)NE * HD * NFF * 2);
  f64x2*    Gx2   = (f64x2*)alloc((size_t)512 * 64 * 16);
  float*    Gq    = (float*)alloc((size_t)512 * 64 * 8);
  double*   gbias = (double*)alloc(64 * 8);
  float*    tkw   = (float*)alloc((size_t)NT * 2 * 4);
  int*      lists = (int*)alloc((size_t)NE * NT * 4);
  int*      cnt   = (int*)alloc(512 * 4);
  _Float16* slots = (_Float16*)alloc((size_t)NT * 2 * HD * 2);
  (void)in_sizes; (void)n_in; (void)out_size; (void)ws_size;

  prep_kernel<<<3328, dim3(32, 8), 0, stream>>>(split_W, merge_W, W1, W2, split_b, gate_W, gate_b,
                                                sWt, mWt, W1t, W2t, (double*)Gx2, Gq, gbias, cnt);
  // gate also produces x_h (fused convert), so it runs before the split GEMM
  gate_kernel<<<512, 256, 0, stream>>>(x, Gq, Gx2, gbias, x_h, tkw, lists, cnt);
  // t = x @ split_W + split_b   (fp16 out for downstream MFMA)
  gemm_f16_kernel<<<dim3(8, 64), 256, 0, stream>>>(x_h, sWt, split_b, nullptr, t_h, NBS, ND, ND);
  expert_kernel<<<NE * 512, 512, 0, stream>>>(t_h, W1t, W2t, b1, b2, cnt, lists, tkw, slots);
  combine_ln_kernel<<<NT / 4, 256, 0, stream>>>(slots, momentum, t_h, ln_g, ln_b, nm_out, out_h);
  // final = out @ merge_W + merge_b
  gemm_f16_kernel<<<dim3(8, 64), 256, 0, stream>>>(out_h, mWt, merge_b, final_out, nullptr, NBS, ND, ND);
}